// Round 2
// baseline (8997.786 us; speedup 1.0000x reference)
//
#include <hip/hip_runtime.h>
#include <math.h>

#define T_LEN 4096
#define DMODEL 2048
#define NH 16
#define CQKV 6144
#define CQKVZ 8192
#define SCALE 0.08838834764831845f   // 128^-0.5

__device__ __forceinline__ float siluf(float x) { return x / (1.0f + __expf(-x)); }

// ---------------- RMSNorm over D=2048 ----------------
__global__ __launch_bounds__(256) void rmsnorm_kernel(const float* __restrict__ x,
                                                      const float* __restrict__ w,
                                                      float* __restrict__ out) {
  const int t = blockIdx.x;
  const int tid = threadIdx.x;
  const float4* xr = (const float4*)(x + (size_t)t * DMODEL);
  float4 v0 = xr[tid];
  float4 v1 = xr[tid + 256];
  float s = v0.x*v0.x + v0.y*v0.y + v0.z*v0.z + v0.w*v0.w
          + v1.x*v1.x + v1.y*v1.y + v1.z*v1.z + v1.w*v1.w;
#pragma unroll
  for (int off = 32; off > 0; off >>= 1) s += __shfl_down(s, off);
  __shared__ float red[4];
  if ((tid & 63) == 0) red[tid >> 6] = s;
  __syncthreads();
  const float tot = red[0] + red[1] + red[2] + red[3];
  const float r = rsqrtf(tot * (1.0f / DMODEL) + 1e-5f);
  const float4* wr = (const float4*)w;
  const float4 w0 = wr[tid], w1 = wr[tid + 256];
  float4 o0, o1;
  o0.x = v0.x*r*w0.x; o0.y = v0.y*r*w0.y; o0.z = v0.z*r*w0.z; o0.w = v0.w*r*w0.w;
  o1.x = v1.x*r*w1.x; o1.y = v1.y*r*w1.y; o1.z = v1.z*r*w1.z; o1.w = v1.w*r*w1.w;
  float4* orow = (float4*)(out + (size_t)t * DMODEL);
  orow[tid] = o0;
  orow[tid + 256] = o1;
}

// ---------------- C[M][N] (+)= A[M][K] * B[N][K]^T ----------------
template<int ACCUM>
__global__ __launch_bounds__(256) void gemm_nt_kernel(const float* __restrict__ A,
                                                      const float* __restrict__ B,
                                                      float* __restrict__ C,
                                                      int M, int N, int K) {
  __shared__ __align__(16) float As[16][132];
  __shared__ __align__(16) float Bs[16][132];
  const int bm = blockIdx.y * 128;
  const int bn = blockIdx.x * 128;
  const int tid = threadIdx.x;
  const int tx = tid & 15;
  const int ty = tid >> 4;
  const int lr = tid >> 1;
  const int lc = (tid & 1) * 8;
  const float* Ag = A + (size_t)(bm + lr) * K + lc;
  const float* Bg = B + (size_t)(bn + lr) * K + lc;
  float acc[8][8];
#pragma unroll
  for (int i = 0; i < 8; i++)
#pragma unroll
    for (int j = 0; j < 8; j++) acc[i][j] = 0.0f;
  for (int k0 = 0; k0 < K; k0 += 16) {
    const float4 a0 = *(const float4*)(Ag + k0);
    const float4 a1 = *(const float4*)(Ag + k0 + 4);
    const float4 b0 = *(const float4*)(Bg + k0);
    const float4 b1 = *(const float4*)(Bg + k0 + 4);
    As[lc + 0][lr] = a0.x; As[lc + 1][lr] = a0.y; As[lc + 2][lr] = a0.z; As[lc + 3][lr] = a0.w;
    As[lc + 4][lr] = a1.x; As[lc + 5][lr] = a1.y; As[lc + 6][lr] = a1.z; As[lc + 7][lr] = a1.w;
    Bs[lc + 0][lr] = b0.x; Bs[lc + 1][lr] = b0.y; Bs[lc + 2][lr] = b0.z; Bs[lc + 3][lr] = b0.w;
    Bs[lc + 4][lr] = b1.x; Bs[lc + 5][lr] = b1.y; Bs[lc + 6][lr] = b1.z; Bs[lc + 7][lr] = b1.w;
    __syncthreads();
#pragma unroll
    for (int kk = 0; kk < 16; kk++) {
      const float4 av0 = *(const float4*)&As[kk][ty * 8];
      const float4 av1 = *(const float4*)&As[kk][ty * 8 + 4];
      const float4 bv0 = *(const float4*)&Bs[kk][tx * 8];
      const float4 bv1 = *(const float4*)&Bs[kk][tx * 8 + 4];
      const float a[8] = {av0.x, av0.y, av0.z, av0.w, av1.x, av1.y, av1.z, av1.w};
      const float b[8] = {bv0.x, bv0.y, bv0.z, bv0.w, bv1.x, bv1.y, bv1.z, bv1.w};
#pragma unroll
      for (int i = 0; i < 8; i++)
#pragma unroll
        for (int j = 0; j < 8; j++) acc[i][j] += a[i] * b[j];
    }
    __syncthreads();
  }
#pragma unroll
  for (int i = 0; i < 8; i++) {
    float* Cp = C + (size_t)(bm + ty * 8 + i) * N + bn + tx * 8;
    float4 c0, c1;
    c0.x = acc[i][0]; c0.y = acc[i][1]; c0.z = acc[i][2]; c0.w = acc[i][3];
    c1.x = acc[i][4]; c1.y = acc[i][5]; c1.z = acc[i][6]; c1.w = acc[i][7];
    if (ACCUM) {
      const float4 d0 = *(const float4*)Cp;
      const float4 d1 = *(const float4*)(Cp + 4);
      c0.x += d0.x; c0.y += d0.y; c0.z += d0.z; c0.w += d0.w;
      c1.x += d1.x; c1.y += d1.y; c1.z += d1.z; c1.w += d1.w;
    }
    *(float4*)Cp = c0;
    *(float4*)(Cp + 4) = c1;
  }
}

// ---------------- up-GEMM with fused silu(gate)*up, in place over gate buffer ----------------
__global__ __launch_bounds__(256) void gemm_nt_silu_kernel(const float* __restrict__ A,
                                                           const float* __restrict__ B,
                                                           float* __restrict__ C,  // gate in, combined out
                                                           int M, int N, int K) {
  __shared__ __align__(16) float As[16][132];
  __shared__ __align__(16) float Bs[16][132];
  const int bm = blockIdx.y * 128;
  const int bn = blockIdx.x * 128;
  const int tid = threadIdx.x;
  const int tx = tid & 15;
  const int ty = tid >> 4;
  const int lr = tid >> 1;
  const int lc = (tid & 1) * 8;
  const float* Ag = A + (size_t)(bm + lr) * K + lc;
  const float* Bg = B + (size_t)(bn + lr) * K + lc;
  float acc[8][8];
#pragma unroll
  for (int i = 0; i < 8; i++)
#pragma unroll
    for (int j = 0; j < 8; j++) acc[i][j] = 0.0f;
  for (int k0 = 0; k0 < K; k0 += 16) {
    const float4 a0 = *(const float4*)(Ag + k0);
    const float4 a1 = *(const float4*)(Ag + k0 + 4);
    const float4 b0 = *(const float4*)(Bg + k0);
    const float4 b1 = *(const float4*)(Bg + k0 + 4);
    As[lc + 0][lr] = a0.x; As[lc + 1][lr] = a0.y; As[lc + 2][lr] = a0.z; As[lc + 3][lr] = a0.w;
    As[lc + 4][lr] = a1.x; As[lc + 5][lr] = a1.y; As[lc + 6][lr] = a1.z; As[lc + 7][lr] = a1.w;
    Bs[lc + 0][lr] = b0.x; Bs[lc + 1][lr] = b0.y; Bs[lc + 2][lr] = b0.z; Bs[lc + 3][lr] = b0.w;
    Bs[lc + 4][lr] = b1.x; Bs[lc + 5][lr] = b1.y; Bs[lc + 6][lr] = b1.z; Bs[lc + 7][lr] = b1.w;
    __syncthreads();
#pragma unroll
    for (int kk = 0; kk < 16; kk++) {
      const float4 av0 = *(const float4*)&As[kk][ty * 8];
      const float4 av1 = *(const float4*)&As[kk][ty * 8 + 4];
      const float4 bv0 = *(const float4*)&Bs[kk][tx * 8];
      const float4 bv1 = *(const float4*)&Bs[kk][tx * 8 + 4];
      const float a[8] = {av0.x, av0.y, av0.z, av0.w, av1.x, av1.y, av1.z, av1.w};
      const float b[8] = {bv0.x, bv0.y, bv0.z, bv0.w, bv1.x, bv1.y, bv1.z, bv1.w};
#pragma unroll
      for (int i = 0; i < 8; i++)
#pragma unroll
        for (int j = 0; j < 8; j++) acc[i][j] += a[i] * b[j];
    }
    __syncthreads();
  }
#pragma unroll
  for (int i = 0; i < 8; i++) {
    float* Cp = C + (size_t)(bm + ty * 8 + i) * N + bn + tx * 8;
    const float4 g0 = *(const float4*)Cp;
    const float4 g1 = *(const float4*)(Cp + 4);
    float4 c0, c1;
    c0.x = siluf(g0.x) * acc[i][0]; c0.y = siluf(g0.y) * acc[i][1];
    c0.z = siluf(g0.z) * acc[i][2]; c0.w = siluf(g0.w) * acc[i][3];
    c1.x = siluf(g1.x) * acc[i][4]; c1.y = siluf(g1.y) * acc[i][5];
    c1.z = siluf(g1.z) * acc[i][6]; c1.w = siluf(g1.w) * acc[i][7];
    *(float4*)Cp = c0;
    *(float4*)(Cp + 4) = c1;
  }
}

// ---------------- ba = h @ ba_w^T  (N=32, tiny) ----------------
__global__ __launch_bounds__(256) void ba_gemm_kernel(const float* __restrict__ h_in,
                                                      const float* __restrict__ ba_w,
                                                      float* __restrict__ ba_out) {
  __shared__ __align__(16) float hl[2048];
  __shared__ float red[32][9];
  const int t = blockIdx.x;
  const int tid = threadIdx.x;
  const float4* hr = (const float4*)(h_in + (size_t)t * DMODEL);
  ((float4*)hl)[tid] = hr[tid];
  ((float4*)hl)[tid + 256] = hr[tid + 256];
  __syncthreads();
  const int c = tid & 31;
  const int p = tid >> 5;
  const float* wrow = ba_w + (size_t)c * DMODEL + p * 256;
  const float* hrow = hl + p * 256;
  float s = 0.f;
#pragma unroll 8
  for (int k = 0; k < 256; k++) s += hrow[k] * wrow[k];
  red[c][p] = s;
  __syncthreads();
  if (tid < 32) {
    float tot = 0.f;
#pragma unroll
    for (int q = 0; q < 8; q++) tot += red[tid][q];
    ba_out[(size_t)t * 32 + tid] = tot;
  }
}

// ---------------- extract z columns from qkvz ----------------
__global__ __launch_bounds__(256) void zcopy_kernel(const float* __restrict__ qkvz,
                                                    float* __restrict__ z) {
  const int idx = blockIdx.x * 256 + threadIdx.x;  // over T*2048/4 float4s
  const int t = idx >> 9;
  const int c4 = (idx & 511) * 4;
  *(float4*)(z + (size_t)t * 2048 + c4) =
      *(const float4*)(qkvz + (size_t)t * CQKVZ + CQKV + c4);
}

// ---------------- causal depthwise conv (K=4) + SiLU ----------------
__global__ __launch_bounds__(256) void conv_silu_kernel(const float* __restrict__ qkvz,
                                                        const float* __restrict__ conv_w,
                                                        const float* __restrict__ mask,
                                                        float* __restrict__ mixed) {
  const int idx = blockIdx.x * 256 + threadIdx.x;   // over T*6144/4 float4s
  const int c4 = (idx % 1536) * 4;
  const int t = idx / 1536;
  const float4 w0 = *(const float4*)(conv_w + (size_t)c4 * 4);
  const float4 w1 = *(const float4*)(conv_w + (size_t)c4 * 4 + 4);
  const float4 w2 = *(const float4*)(conv_w + (size_t)c4 * 4 + 8);
  const float4 w3 = *(const float4*)(conv_w + (size_t)c4 * 4 + 12);
  const float wj0[4] = {w0.x, w0.y, w0.z, w0.w};
  const float wj1[4] = {w1.x, w1.y, w1.z, w1.w};
  const float wj2[4] = {w2.x, w2.y, w2.z, w2.w};
  const float wj3[4] = {w3.x, w3.y, w3.z, w3.w};
  float4 acc = make_float4(0.f, 0.f, 0.f, 0.f);
#pragma unroll
  for (int j = 0; j < 4; j++) {
    const int tt = t - 3 + j;
    if (tt < 0) continue;
    const float m = mask[tt];
    const float4 xv = *(const float4*)(qkvz + (size_t)tt * CQKVZ + c4);
    acc.x += xv.x * m * wj0[j];
    acc.y += xv.y * m * wj1[j];
    acc.z += xv.z * m * wj2[j];
    acc.w += xv.w * m * wj3[j];
  }
  acc.x = siluf(acc.x); acc.y = siluf(acc.y); acc.z = siluf(acc.z); acc.w = siluf(acc.w);
  *(float4*)(mixed + (size_t)t * CQKV + c4) = acc;
}

// ---------------- l2norm over Dk=128 for q,k heads (in place) ----------------
__global__ __launch_bounds__(256) void l2norm_kernel(float* __restrict__ mixed) {
  const int r = blockIdx.x * 4 + (threadIdx.x >> 6);  // r = t*32 + hh, hh in [0,32)
  const int lane = threadIdx.x & 63;
  const int t = r >> 5;
  const int hh = r & 31;
  float* p = mixed + (size_t)t * CQKV + hh * 128 + lane * 2;
  float2 v = *(float2*)p;
  float s = v.x * v.x + v.y * v.y;
#pragma unroll
  for (int off = 32; off > 0; off >>= 1) s += __shfl_down(s, off);
  s = __shfl(s, 0);
  const float rn = rsqrtf(s + 1e-6f);
  v.x *= rn; v.y *= rn;
  *(float2*)p = v;
}

// ---------------- beta, g ----------------
__global__ __launch_bounds__(256) void beta_g_kernel(const float* __restrict__ ba,
                                                     const float* __restrict__ A_log,
                                                     const float* __restrict__ dt_bias,
                                                     const float* __restrict__ mask,
                                                     float* __restrict__ beta,
                                                     float* __restrict__ g) {
  const int idx = blockIdx.x * 256 + threadIdx.x;  // t*16 + h
  const int t = idx >> 4;
  const int h = idx & 15;
  const float b = ba[(size_t)t * 32 + h];
  const float a = ba[(size_t)t * 32 + 16 + h];
  const float m = mask[t];
  beta[idx] = m / (1.0f + expf(-b));
  const float xx = a + dt_bias[h];
  const float sp = (xx > 20.0f) ? xx : log1pf(expf(xx));
  g[idx] = -expf(A_log[h]) * sp * m;
}

// ---------------- per-chunk cumsum of g ----------------
__global__ __launch_bounds__(256) void gcs_kernel(const float* __restrict__ g,
                                                  float* __restrict__ gcsbuf) {
  const int idx = blockIdx.x * 256 + threadIdx.x;  // chunk id = h*64 + n
  if (idx >= 1024) return;
  const int h = idx >> 6;
  const int n = idx & 63;
  const int t0 = n * 64;
  float s = 0.f;
  for (int i = 0; i < 64; i++) {
    s += g[(size_t)(t0 + i) * NH + h];
    gcsbuf[(size_t)idx * 64 + i] = s;
  }
}

// ---------------- per-chunk: A = (k_beta k^T)*decay (strict lower), attn = (q k^T)*decay*scale (lower) ----------------
__global__ __launch_bounds__(256) void pre_attn_kernel(const float* __restrict__ mixed,
                                                       const float* __restrict__ gcsbuf,
                                                       const float* __restrict__ betabuf,
                                                       float* __restrict__ abuf,
                                                       float* __restrict__ attnbuf) {
  __shared__ __align__(16) float kl[64][132];
  __shared__ float gcs_s[64];
  __shared__ float betal[64];
  const int blk = blockIdx.x;
  const int h = blk >> 6;
  const int n = blk & 63;
  const int t0 = n * 64;
  const int tid = threadIdx.x;
  if (tid < 64) {
    gcs_s[tid] = gcsbuf[(size_t)blk * 64 + tid];
    betal[tid] = betabuf[(size_t)(t0 + tid) * NH + h];
  }
#pragma unroll
  for (int rep = 0; rep < 8; rep++) {
    const int lin = rep * 256 + tid;
    const int i = lin >> 5;
    const int d = (lin & 31) * 4;
    const float4 kv = *(const float4*)(mixed + (size_t)(t0 + i) * CQKV + 2048 + h * 128 + d);
    *(float4*)&kl[i][d] = kv;
  }
  __syncthreads();
  const int cj = tid & 15;
  const int ri = tid >> 4;
  const int i0 = ri * 4, j0 = cj * 4;
  float accA[4][4], accQ[4][4];
#pragma unroll
  for (int a = 0; a < 4; a++)
#pragma unroll
    for (int b = 0; b < 4; b++) { accA[a][b] = 0.f; accQ[a][b] = 0.f; }
  const float* qbase = mixed + (size_t)t0 * CQKV + h * 128;
#pragma unroll 4
  for (int d = 0; d < 128; d++) {
    const float kj0 = kl[j0][d], kj1 = kl[j0 + 1][d], kj2 = kl[j0 + 2][d], kj3 = kl[j0 + 3][d];
#pragma unroll
    for (int a = 0; a < 4; a++) {
      const float ka = kl[i0 + a][d];
      const float qa = qbase[(size_t)(i0 + a) * CQKV + d];
      accA[a][0] += ka * kj0; accA[a][1] += ka * kj1; accA[a][2] += ka * kj2; accA[a][3] += ka * kj3;
      accQ[a][0] += qa * kj0; accQ[a][1] += qa * kj1; accQ[a][2] += qa * kj2; accQ[a][3] += qa * kj3;
    }
  }
#pragma unroll
  for (int a = 0; a < 4; a++) {
    const int i = i0 + a;
    const float gi = gcs_s[i];
    const float bi = betal[i];
    float4 Av, Qv;
    float dec;
    dec = __expf(fminf(gi - gcs_s[j0 + 0], 0.f));
    Av.x = (i > j0 + 0) ? accA[a][0] * bi * dec : 0.f;
    Qv.x = (i >= j0 + 0) ? accQ[a][0] * dec * SCALE : 0.f;
    dec = __expf(fminf(gi - gcs_s[j0 + 1], 0.f));
    Av.y = (i > j0 + 1) ? accA[a][1] * bi * dec : 0.f;
    Qv.y = (i >= j0 + 1) ? accQ[a][1] * dec * SCALE : 0.f;
    dec = __expf(fminf(gi - gcs_s[j0 + 2], 0.f));
    Av.z = (i > j0 + 2) ? accA[a][2] * bi * dec : 0.f;
    Qv.z = (i >= j0 + 2) ? accQ[a][2] * dec * SCALE : 0.f;
    dec = __expf(fminf(gi - gcs_s[j0 + 3], 0.f));
    Av.w = (i > j0 + 3) ? accA[a][3] * bi * dec : 0.f;
    Qv.w = (i >= j0 + 3) ? accQ[a][3] * dec * SCALE : 0.f;
    *(float4*)(abuf + (size_t)blk * 4096 + i * 64 + j0) = Av;
    *(float4*)(attnbuf + (size_t)blk * 4096 + i * 64 + j0) = Qv;
  }
}

// ---------------- per-chunk: T = (I+A)^-1, then T *= beta[col] ----------------
__global__ __launch_bounds__(256) void pre_solve_kernel(const float* __restrict__ abuf,
                                                        const float* __restrict__ betabuf,
                                                        float* __restrict__ tbuf) {
  __shared__ float Al[64][65];
  __shared__ float Tl[64][65];
  const int blk = blockIdx.x;
  const int h = blk >> 6;
  const int n = blk & 63;
  const int t0 = n * 64;
  const int tid = threadIdx.x;
#pragma unroll
  for (int rep = 0; rep < 4; rep++) {
    const int lin = rep * 256 + tid;
    const int i = lin >> 4;
    const int j = (lin & 15) * 4;
    const float4 av = *(const float4*)(abuf + (size_t)blk * 4096 + i * 64 + j);
    Al[i][j] = av.x; Al[i][j + 1] = av.y; Al[i][j + 2] = av.z; Al[i][j + 3] = av.w;
  }
  __syncthreads();
  if (tid < 64) {
    const int j = tid;
    const float bj = betabuf[(size_t)(t0 + j) * NH + h];
    for (int i = 0; i < 64; i++) {
      float s = (i == j) ? 1.0f : 0.0f;
      for (int l = j; l < i; l++) s -= Al[i][l] * Tl[l][j];
      Tl[i][j] = s;
    }
    for (int i = j; i < 64; i++) Tl[i][j] *= bj;
  }
  __syncthreads();
#pragma unroll
  for (int rep = 0; rep < 4; rep++) {
    const int lin = rep * 256 + tid;
    const int i = lin >> 4;
    const int j = (lin & 15) * 4;
    float4 tv;
    tv.x = Tl[i][j]; tv.y = Tl[i][j + 1]; tv.z = Tl[i][j + 2]; tv.w = Tl[i][j + 3];
    *(float4*)(tbuf + (size_t)blk * 4096 + i * 64 + j) = tv;
  }
}

// ---------------- per-chunk: u = Tb @ v ; w = Tb @ (k * e^gcs) ----------------
__global__ __launch_bounds__(256) void pre_uw_kernel(const float* __restrict__ mixed,
                                                     const float* __restrict__ tbuf,
                                                     const float* __restrict__ gcsbuf,
                                                     float* __restrict__ ubuf,
                                                     float* __restrict__ wbuf) {
  __shared__ __align__(16) float Tl[64][68];
  __shared__ __align__(16) float xl[64][132];
  __shared__ float egcs[64];
  const int blk = blockIdx.x;
  const int h = blk >> 6;
  const int n = blk & 63;
  const int t0 = n * 64;
  const int tid = threadIdx.x;
  if (tid < 64) egcs[tid] = __expf(gcsbuf[(size_t)blk * 64 + tid]);
#pragma unroll
  for (int rep = 0; rep < 4; rep++) {
    const int lin = rep * 256 + tid;
    const int i = lin >> 4;
    const int j = (lin & 15) * 4;
    const float4 tv = *(const float4*)(tbuf + (size_t)blk * 4096 + i * 64 + j);
    *(float4*)&Tl[i][j] = tv;
  }
#pragma unroll
  for (int rep = 0; rep < 8; rep++) {
    const int lin = rep * 256 + tid;
    const int i = lin >> 5;
    const int d = (lin & 31) * 4;
    const float4 vv = *(const float4*)(mixed + (size_t)(t0 + i) * CQKV + 4096 + h * 128 + d);
    *(float4*)&xl[i][d] = vv;
  }
  __syncthreads();
  const int cgu = tid & 15;
  const int riu = tid >> 4;
  const int i0 = riu * 4;
  const int d0 = cgu * 8;
  float acc[4][8];
#pragma unroll
  for (int a = 0; a < 4; a++)
#pragma unroll
    for (int b = 0; b < 8; b++) acc[a][b] = 0.f;
#pragma unroll 2
  for (int j = 0; j < 64; j++) {
    const float tv[4] = {Tl[i0][j], Tl[i0 + 1][j], Tl[i0 + 2][j], Tl[i0 + 3][j]};
    const float4 x0 = *(const float4*)&xl[j][d0];
    const float4 x1 = *(const float4*)&xl[j][d0 + 4];
    const float xv[8] = {x0.x, x0.y, x0.z, x0.w, x1.x, x1.y, x1.z, x1.w};
#pragma unroll
    for (int a = 0; a < 4; a++)
#pragma unroll
      for (int b = 0; b < 8; b++) acc[a][b] += tv[a] * xv[b];
  }
#pragma unroll
  for (int a = 0; a < 4; a++) {
    float* up = ubuf + (size_t)(t0 + i0 + a) * 2048 + h * 128 + d0;
    *(float4*)up = make_float4(acc[a][0], acc[a][1], acc[a][2], acc[a][3]);
    *(float4*)(up + 4) = make_float4(acc[a][4], acc[a][5], acc[a][6], acc[a][7]);
  }
  __syncthreads();
#pragma unroll
  for (int rep = 0; rep < 8; rep++) {
    const int lin = rep * 256 + tid;
    const int i = lin >> 5;
    const int d = (lin & 31) * 4;
    float4 kv = *(const float4*)(mixed + (size_t)(t0 + i) * CQKV + 2048 + h * 128 + d);
    const float e = egcs[i];
    kv.x *= e; kv.y *= e; kv.z *= e; kv.w *= e;
    *(float4*)&xl[i][d] = kv;
  }
  __syncthreads();
#pragma unroll
  for (int a = 0; a < 4; a++)
#pragma unroll
    for (int b = 0; b < 8; b++) acc[a][b] = 0.f;
#pragma unroll 2
  for (int j = 0; j < 64; j++) {
    const float tv[4] = {Tl[i0][j], Tl[i0 + 1][j], Tl[i0 + 2][j], Tl[i0 + 3][j]};
    const float4 x0 = *(const float4*)&xl[j][d0];
    const float4 x1 = *(const float4*)&xl[j][d0 + 4];
    const float xv[8] = {x0.x, x0.y, x0.z, x0.w, x1.x, x1.y, x1.z, x1.w};
#pragma unroll
    for (int a = 0; a < 4; a++)
#pragma unroll
      for (int b = 0; b < 8; b++) acc[a][b] += tv[a] * xv[b];
  }
#pragma unroll
  for (int a = 0; a < 4; a++) {
    float* wp = wbuf + (size_t)(t0 + i0 + a) * 2048 + h * 128 + d0;
    *(float4*)wp = make_float4(acc[a][0], acc[a][1], acc[a][2], acc[a][3]);
    *(float4*)(wp + 4) = make_float4(acc[a][4], acc[a][5], acc[a][6], acc[a][7]);
  }
}

// ---------------- sequential chunk scan; grid = 16 heads x 4 col-slices ----------------
__global__ __launch_bounds__(512) void seq_kernel(const float* __restrict__ mixed,
                                                  const float* __restrict__ ubuf,
                                                  const float* __restrict__ wbuf,
                                                  const float* __restrict__ attnbuf,
                                                  const float* __restrict__ gcsbuf,
                                                  float* __restrict__ obuf) {
  __shared__ __align__(16) float S[128][36];
  __shared__ __align__(16) float vn[64][36];
  __shared__ float wl[64][129];
  __shared__ float gcs_s[64];
  __shared__ float egq[64];
  __shared__ float edk[64];
  const int h = blockIdx.x >> 2;
  const int sl = blockIdx.x & 3;
  const int jb = sl * 32;
  const int tid = threadIdx.x;
  const int cg = tid & 7;
  const int iv = tid >> 3;
  for (int lin = tid; lin < 128 * 32; lin += 512) S[lin >> 5][lin & 31] = 0.0f;
  for (int n = 0; n < 64; n++) {
    const int t0 = n * 64;
    const int blk = h * 64 + n;
    __syncthreads();
    if (tid < 64) gcs_s[tid] = gcsbuf[(size_t)blk * 64 + tid];
    __syncthreads();
    if (tid < 64) {
      const float glast = gcs_s[63];
      egq[tid] = __expf(gcs_s[tid]) * SCALE;
      edk[tid] = __expf(glast - gcs_s[tid]);
    }
#pragma unroll
    for (int rep = 0; rep < 4; rep++) {
      const int lin = rep * 512 + tid;
      const int i = lin >> 5;
      const int d = (lin & 31) * 4;
      const float4 wv = *(const float4*)(wbuf + (size_t)(t0 + i) * 2048 + h * 128 + d);
      wl[i][d] = wv.x; wl[i][d + 1] = wv.y; wl[i][d + 2] = wv.z; wl[i][d + 3] = wv.w;
    }
    __syncthreads();
    // v_new = u - w @ S
    {
      float4 acc = *(const float4*)(ubuf + (size_t)(t0 + iv) * 2048 + h * 128 + jb + cg * 4);
#pragma unroll 8
      for (int k = 0; k < 128; k++) {
        const float wv = wl[iv][k];
        const float4 sv = *(const float4*)&S[k][cg * 4];
        acc.x -= wv * sv.x; acc.y -= wv * sv.y; acc.z -= wv * sv.z; acc.w -= wv * sv.w;
      }
      *(float4*)&vn[iv][cg * 4] = acc;
    }
    __syncthreads();
    // o = (q * scale * e^gcs) @ S + attn @ v_new
    {
      float4 acc = make_float4(0.f, 0.f, 0.f, 0.f);
      const float* qrow = mixed + (size_t)(t0 + iv) * CQKV + h * 128;
      const float eq = egq[iv];
#pragma unroll 8
      for (int k = 0; k < 128; k++) {
        const float qv = qrow[k] * eq;
        const float4 sv = *(const float4*)&S[k][cg * 4];
        acc.x += qv * sv.x; acc.y += qv * sv.y; acc.z += qv * sv.z; acc.w += qv * sv.w;
      }
      const float* arow = attnbuf + (size_t)blk * 4096 + iv * 64;
#pragma unroll 8
      for (int l = 0; l < 64; l++) {
        const float av = arow[l];
        const float4 vv = *(const float4*)&vn[l][cg * 4];
        acc.x += av * vv.x; acc.y += av * vv.y; acc.z += av * vv.z; acc.w += av * vv.w;
      }
      *(float4*)(obuf + (size_t)(t0 + iv) * 2048 + h * 128 + jb + cg * 4) = acc;
    }
    // S = S * e^glast + kdec^T @ v_new
    float a00 = 0.f, a01 = 0.f, a02 = 0.f, a03 = 0.f;
    float a10 = 0.f, a11 = 0.f, a12 = 0.f, a13 = 0.f;
#pragma unroll 4
    for (int l = 0; l < 64; l++) {
      const float* krow = mixed + (size_t)(t0 + l) * CQKV + 2048 + h * 128;
      const float ed = edk[l];
      const float k0 = krow[iv] * ed;
      const float k1 = krow[iv + 64] * ed;
      const float4 vv = *(const float4*)&vn[l][cg * 4];
      a00 += k0 * vv.x; a01 += k0 * vv.y; a02 += k0 * vv.z; a03 += k0 * vv.w;
      a10 += k1 * vv.x; a11 += k1 * vv.y; a12 += k1 * vv.z; a13 += k1 * vv.w;
    }
    const float eglast = __expf(gcs_s[63]);
    __syncthreads();
    {
      float4 s0 = *(const float4*)&S[iv][cg * 4];
      s0.x = s0.x * eglast + a00; s0.y = s0.y * eglast + a01;
      s0.z = s0.z * eglast + a02; s0.w = s0.w * eglast + a03;
      *(float4*)&S[iv][cg * 4] = s0;
      float4 s1 = *(const float4*)&S[iv + 64][cg * 4];
      s1.x = s1.x * eglast + a10; s1.y = s1.y * eglast + a11;
      s1.z = s1.z * eglast + a12; s1.w = s1.w * eglast + a13;
      *(float4*)&S[iv + 64][cg * 4] = s1;
    }
  }
}

// ---------------- gated RMSNorm over Dv=128: o = rms(o)*w*silu(z) ----------------
__global__ __launch_bounds__(256) void onorm_kernel(float* __restrict__ o,
                                                    const float* __restrict__ z,
                                                    const float* __restrict__ w) {
  const int r = blockIdx.x * 4 + (threadIdx.x >> 6);  // r = t*16 + h
  const int lane = threadIdx.x & 63;
  const int t = r >> 4;
  const int h = r & 15;
  float* op = o + (size_t)t * 2048 + h * 128 + lane * 2;
  float2 v = *(float2*)op;
  float s = v.x * v.x + v.y * v.y;
#pragma unroll
  for (int off = 32; off > 0; off >>= 1) s += __shfl_down(s, off);
  s = __shfl(s, 0);
  const float rn = rsqrtf(s * (1.0f / 128.0f) + 1e-5f);
  const float2 wv = *(const float2*)(w + lane * 2);
  const float2 zv = *(const float2*)(z + (size_t)t * 2048 + h * 128 + lane * 2);
  v.x = v.x * rn * wv.x * siluf(zv.x);
  v.y = v.y * rn * wv.y * siluf(zv.y);
  *(float2*)op = v;
}

// ---------------- helpers ----------------
__global__ __launch_bounds__(256) void copy_kernel(const float* __restrict__ in,
                                                   float* __restrict__ out) {
  const int i = blockIdx.x * 256 + threadIdx.x;
  ((float4*)out)[i] = ((const float4*)in)[i];
}

extern "C" void kernel_launch(void* const* d_in, const int* in_sizes, int n_in,
                              void* d_out, int out_size, void* d_ws, size_t ws_size,
                              hipStream_t stream) {
  (void)in_sizes; (void)n_in; (void)out_size;
  const float* x        = (const float*)d_in[0];
  const float* mask     = (const float*)d_in[1];
  const float* ln1_w    = (const float*)d_in[2];
  const float* qkvz_w   = (const float*)d_in[3];
  const float* ba_w     = (const float*)d_in[4];
  const float* conv_w   = (const float*)d_in[5];
  const float* A_log    = (const float*)d_in[6];
  const float* dt_bias  = (const float*)d_in[7];
  const float* o_norm_w = (const float*)d_in[8];
  const float* out_w    = (const float*)d_in[9];
  const float* ln2_w    = (const float*)d_in[10];
  const float* gate_w   = (const float*)d_in[11];
  const float* up_w     = (const float*)d_in[12];
  const float* down_w   = (const float*)d_in[13];
  float* out = (float*)d_out;

  // ---- workspace layout (floats), liveness-aliased; total 75,825,152 floats = 289.3 MB ----
  // A [0, 8388608):        h -> (a_buf, t_buf) -> o -> h2
  // Z [8388608, 16777216): z columns of qkvz
  // B [16777216, 50331648): qkvz -> (attn, u, w) -> gate/combined
  // C [50331648, 75497472): mixed
  // D [75497472, 75825152): ba, beta, g, gcs
  const size_t NEED_BYTES = (size_t)75825152 * 4;
  if (ws_size < NEED_BYTES) return;  // clean deterministic fail (diagnostic)

  float* ws        = (float*)d_ws;
  float* A_region  = ws;                        // 8,388,608
  float* z_buf     = ws + 8388608;              // 8,388,608
  float* B_region  = ws + 16777216;             // 33,554,432
  float* mixed_buf = ws + 50331648;             // 25,165,824
  float* ba_buf    = ws + 75497472;             // 131,072
  float* beta_buf  = ws + 75628544;             // 65,536
  float* g_buf     = ws + 75694080;             // 65,536
  float* gcs_buf   = ws + 75759616;             // 65,536

  float* h_buf     = A_region;                  // phase 1
  float* a_buf     = A_region;                  // 4,194,304 (after h dead)
  float* t_buf     = A_region + 4194304;        // 4,194,304
  float* o_buf     = A_region;                  // 8,388,608 (after a,t dead)
  float* h2_buf    = A_region;                  // (after o dead)

  float* qkvz_buf  = B_region;                  // phase 1-2
  float* attn_buf  = B_region;                  // 4,194,304 (after qkvz dead)
  float* u_buf     = B_region + 4194304;        // 8,388,608
  float* w_buf     = B_region + 12582912;       // 8,388,608
  float* gate_buf  = B_region;                  // 33,554,432 (MLP phase)

  // h = rms(x, ln1_w)
  rmsnorm_kernel<<<4096, 256, 0, stream>>>(x, ln1_w, h_buf);
  // qkvz = h @ qkvz_w^T
  gemm_nt_kernel<0><<<dim3(64, 32), 256, 0, stream>>>(h_buf, qkvz_w, qkvz_buf, 4096, 8192, 2048);
  // ba = h @ ba_w^T
  ba_gemm_kernel<<<4096, 256, 0, stream>>>(h_buf, ba_w, ba_buf);
  // stash z columns (qkvz region gets reused after conv)
  zcopy_kernel<<<8192, 256, 0, stream>>>(qkvz_buf, z_buf);
  // mixed = silu(causal_conv(concat(q,k,v)*mask))
  conv_silu_kernel<<<24576, 256, 0, stream>>>(qkvz_buf, conv_w, mask, mixed_buf);
  // l2norm q,k heads in place
  l2norm_kernel<<<32768, 256, 0, stream>>>(mixed_buf);
  // beta, g
  beta_g_kernel<<<256, 256, 0, stream>>>(ba_buf, A_log, dt_bias, mask, beta_buf, g_buf);
  // per-chunk cumulative decay
  gcs_kernel<<<4, 256, 0, stream>>>(g_buf, gcs_buf);
  // delta-rule precompute (a_buf/t_buf overlay dead h; attn/u/w overlay dead qkvz)
  pre_attn_kernel<<<1024, 256, 0, stream>>>(mixed_buf, gcs_buf, beta_buf, a_buf, attn_buf);
  pre_solve_kernel<<<1024, 256, 0, stream>>>(a_buf, beta_buf, t_buf);
  pre_uw_kernel<<<1024, 256, 0, stream>>>(mixed_buf, t_buf, gcs_buf, u_buf, w_buf);
  // sequential scan (o overlays dead a/t)
  seq_kernel<<<64, 512, 0, stream>>>(mixed_buf, u_buf, w_buf, attn_buf, gcs_buf, o_buf);
  // gated rmsnorm with z
  onorm_kernel<<<16384, 256, 0, stream>>>(o_buf, z_buf, o_norm_w);
  // x_mid = x + o @ out_w^T  (into d_out)
  copy_kernel<<<8192, 256, 0, stream>>>(x, out);
  gemm_nt_kernel<1><<<dim3(16, 32), 256, 0, stream>>>(o_buf, out_w, out, 4096, 2048, 2048);
  // h2 = rms(x_mid, ln2_w)  (overlays dead o)
  rmsnorm_kernel<<<4096, 256, 0, stream>>>(out, ln2_w, h2_buf);
  // mlp: gate -> B; up fused with silu(gate)*up in place; down accumulates into d_out
  gemm_nt_kernel<0><<<dim3(64, 32), 256, 0, stream>>>(h2_buf, gate_w, gate_buf, 4096, 8192, 2048);
  gemm_nt_silu_kernel<<<dim3(64, 32), 256, 0, stream>>>(h2_buf, up_w, gate_buf, 4096, 8192, 2048);
  gemm_nt_kernel<1><<<dim3(16, 32), 256, 0, stream>>>(gate_buf, down_w, out, 4096, 2048, 8192);
}

// Round 3
// 2826.597 us; speedup vs baseline: 3.1833x; 3.1833x over previous
//
#include <hip/hip_runtime.h>
#include <math.h>

#define T_LEN 4096
#define DMODEL 2048
#define NH 16
#define CQKV 6144
#define CQKVZ 8192
#define SCALE 0.08838834764831845f   // 128^-0.5

using bf16x8 = __attribute__((ext_vector_type(8))) short;
using f32x4  = __attribute__((ext_vector_type(4))) float;

__device__ __forceinline__ float siluf(float x) { return x / (1.0f + __expf(-x)); }

__device__ __forceinline__ unsigned short f2bf(float f) {  // RNE
  unsigned int u = __float_as_uint(f);
  u = (u + 0x7FFFu + ((u >> 16) & 1u)) >> 16;
  return (unsigned short)u;
}
__device__ __forceinline__ float bf2f(unsigned short u) {
  return __uint_as_float(((unsigned int)u) << 16);
}

// ---------------- RMSNorm over D=2048; MODE: 1 = f32+bf16, 2 = bf16 only ----------------
template<int MODE>
__global__ __launch_bounds__(256) void rmsnorm_kernel(const float* __restrict__ x,
                                                      const float* __restrict__ w,
                                                      float* __restrict__ outf,
                                                      unsigned short* __restrict__ outb) {
  const int t = blockIdx.x;
  const int tid = threadIdx.x;
  const float4* xr = (const float4*)(x + (size_t)t * DMODEL);
  float4 v0 = xr[tid];
  float4 v1 = xr[tid + 256];
  float s = v0.x*v0.x + v0.y*v0.y + v0.z*v0.z + v0.w*v0.w
          + v1.x*v1.x + v1.y*v1.y + v1.z*v1.z + v1.w*v1.w;
#pragma unroll
  for (int off = 32; off > 0; off >>= 1) s += __shfl_down(s, off);
  __shared__ float red[4];
  if ((tid & 63) == 0) red[tid >> 6] = s;
  __syncthreads();
  const float tot = red[0] + red[1] + red[2] + red[3];
  const float r = rsqrtf(tot * (1.0f / DMODEL) + 1e-5f);
  const float4* wr = (const float4*)w;
  const float4 w0 = wr[tid], w1 = wr[tid + 256];
  float4 o0, o1;
  o0.x = v0.x*r*w0.x; o0.y = v0.y*r*w0.y; o0.z = v0.z*r*w0.z; o0.w = v0.w*r*w0.w;
  o1.x = v1.x*r*w1.x; o1.y = v1.y*r*w1.y; o1.z = v1.z*r*w1.z; o1.w = v1.w*r*w1.w;
  if (MODE == 1) {
    float4* orow = (float4*)(outf + (size_t)t * DMODEL);
    orow[tid] = o0;
    orow[tid + 256] = o1;
  }
  ushort4 b0, b1;
  b0.x = f2bf(o0.x); b0.y = f2bf(o0.y); b0.z = f2bf(o0.z); b0.w = f2bf(o0.w);
  b1.x = f2bf(o1.x); b1.y = f2bf(o1.y); b1.z = f2bf(o1.z); b1.w = f2bf(o1.w);
  ushort4* brow = (ushort4*)(outb + (size_t)t * DMODEL);
  brow[tid] = b0;
  brow[tid + 256] = b1;
}

// ---------------- fp32 -> bf16 bulk convert (8 elems/thread, exact grid) ----------------
__global__ __launch_bounds__(256) void f2b_kernel(const float* __restrict__ in,
                                                  unsigned short* __restrict__ out) {
  const size_t i = (size_t)blockIdx.x * 256 + threadIdx.x;
  const float4 a = ((const float4*)in)[2 * i];
  const float4 b = ((const float4*)in)[2 * i + 1];
  ushort4 r0, r1;
  r0.x = f2bf(a.x); r0.y = f2bf(a.y); r0.z = f2bf(a.z); r0.w = f2bf(a.w);
  r1.x = f2bf(b.x); r1.y = f2bf(b.y); r1.z = f2bf(b.z); r1.w = f2bf(b.w);
  ((ushort4*)out)[2 * i] = r0;
  ((ushort4*)out)[2 * i + 1] = r1;
}

// ---------------- bf16 MFMA GEMM: C[M][N] = A[M][K] * B[N][K]^T ----------------
// EPI: 0 = bf16 store, 1 = fp32 accumulate, 2 = silu(gate)*acc -> bf16 in place
template<int EPI>
__global__ __launch_bounds__(256) void gemm_bf16_kernel(const unsigned short* __restrict__ A,
                                                        const unsigned short* __restrict__ B,
                                                        float* __restrict__ Cf,
                                                        unsigned short* __restrict__ Cb,
                                                        int M, int N, int K) {
  __shared__ __align__(16) unsigned short As[128 * 40];  // 80B rows: conflict-free period-8
  __shared__ __align__(16) unsigned short Bs[128 * 40];
  const int bm = blockIdx.y * 128;
  const int bn = blockIdx.x * 128;
  const int tid = threadIdx.x;
  const int row = tid >> 1;            // 0..127
  const int co  = (tid & 1) * 16;      // elem offset within 32-elem k-slab
  const unsigned short* Ag = A + (size_t)(bm + row) * K + co;
  const unsigned short* Bg = B + (size_t)(bn + row) * K + co;
  unsigned short* Asw = &As[row * 40 + co];
  unsigned short* Bsw = &Bs[row * 40 + co];
  const int wv = tid >> 6;
  const int ln = tid & 63;
  const int mo = (wv >> 1) * 64;
  const int no = (wv & 1) * 64;
  const int fr = ln & 15;              // fragment row (m or n) within a 16-tile
  const int q8 = (ln >> 4) * 8;        // k offset within 32

  f32x4 acc[4][4];
  const f32x4 zero = {0.f, 0.f, 0.f, 0.f};
#pragma unroll
  for (int mi = 0; mi < 4; mi++)
#pragma unroll
    for (int ni = 0; ni < 4; ni++) acc[mi][ni] = zero;

  for (int k0 = 0; k0 < K; k0 += 32) {
    const uint4 av0 = *(const uint4*)(Ag + k0);
    const uint4 av1 = *(const uint4*)(Ag + k0 + 8);
    const uint4 bv0 = *(const uint4*)(Bg + k0);
    const uint4 bv1 = *(const uint4*)(Bg + k0 + 8);
    __syncthreads();
    *(uint4*)Asw = av0; *(uint4*)(Asw + 8) = av1;
    *(uint4*)Bsw = bv0; *(uint4*)(Bsw + 8) = bv1;
    __syncthreads();
    bf16x8 afr[4], bfr[4];
#pragma unroll
    for (int mi = 0; mi < 4; mi++)
      afr[mi] = *(const bf16x8*)&As[(mo + mi * 16 + fr) * 40 + q8];
#pragma unroll
    for (int ni = 0; ni < 4; ni++)
      bfr[ni] = *(const bf16x8*)&Bs[(no + ni * 16 + fr) * 40 + q8];
#pragma unroll
    for (int mi = 0; mi < 4; mi++)
#pragma unroll
      for (int ni = 0; ni < 4; ni++)
        acc[mi][ni] = __builtin_amdgcn_mfma_f32_16x16x32_bf16(afr[mi], bfr[ni], acc[mi][ni], 0, 0, 0);
  }

  // C/D layout: col = lane&15, row = (lane>>4)*4 + reg   [m89-verified]
  const int cm = (ln >> 4) * 4;
  const int cn = fr;
#pragma unroll
  for (int mi = 0; mi < 4; mi++) {
#pragma unroll
    for (int ni = 0; ni < 4; ni++) {
#pragma unroll
      for (int r = 0; r < 4; r++) {
        const int grow = bm + mo + mi * 16 + cm + r;
        const int gcol = bn + no + ni * 16 + cn;
        const size_t off = (size_t)grow * N + gcol;
        const float v = acc[mi][ni][r];
        if (EPI == 0) {
          Cb[off] = f2bf(v);
        } else if (EPI == 1) {
          Cf[off] += v;
        } else {
          Cb[off] = f2bf(siluf(bf2f(Cb[off])) * v);
        }
      }
    }
  }
}

// ---------------- ba = h @ ba_w^T  (N=32, tiny) ----------------
__global__ __launch_bounds__(256) void ba_gemm_kernel(const float* __restrict__ h_in,
                                                      const float* __restrict__ ba_w,
                                                      float* __restrict__ ba_out) {
  __shared__ __align__(16) float hl[2048];
  __shared__ float red[32][9];
  const int t = blockIdx.x;
  const int tid = threadIdx.x;
  const float4* hr = (const float4*)(h_in + (size_t)t * DMODEL);
  ((float4*)hl)[tid] = hr[tid];
  ((float4*)hl)[tid + 256] = hr[tid + 256];
  __syncthreads();
  const int c = tid & 31;
  const int p = tid >> 5;
  const float* wrow = ba_w + (size_t)c * DMODEL + p * 256;
  const float* hrow = hl + p * 256;
  float s = 0.f;
#pragma unroll 8
  for (int k = 0; k < 256; k++) s += hrow[k] * wrow[k];
  red[c][p] = s;
  __syncthreads();
  if (tid < 32) {
    float tot = 0.f;
#pragma unroll
    for (int q = 0; q < 8; q++) tot += red[tid][q];
    ba_out[(size_t)t * 32 + tid] = tot;
  }
}

// ---------------- extract z columns from bf16 qkvz ----------------
__global__ __launch_bounds__(256) void zcopy_kernel(const unsigned short* __restrict__ qkvz,
                                                    unsigned short* __restrict__ z) {
  const int idx = blockIdx.x * 256 + threadIdx.x;  // over T*2048/8 groups
  const int t = idx >> 8;
  const int c8 = (idx & 255) * 8;
  *(uint4*)(z + (size_t)t * 2048 + c8) =
      *(const uint4*)(qkvz + (size_t)t * CQKVZ + CQKV + c8);
}

// ---------------- causal depthwise conv (K=4) + SiLU; bf16 in, fp32 out ----------------
__global__ __launch_bounds__(256) void conv_silu_kernel(const unsigned short* __restrict__ qkvz,
                                                        const float* __restrict__ conv_w,
                                                        const float* __restrict__ mask,
                                                        float* __restrict__ mixed) {
  const int idx = blockIdx.x * 256 + threadIdx.x;   // over T*6144/4
  const int c4 = (idx % 1536) * 4;
  const int t = idx / 1536;
  const float4 w0 = *(const float4*)(conv_w + (size_t)c4 * 4);
  const float4 w1 = *(const float4*)(conv_w + (size_t)c4 * 4 + 4);
  const float4 w2 = *(const float4*)(conv_w + (size_t)c4 * 4 + 8);
  const float4 w3 = *(const float4*)(conv_w + (size_t)c4 * 4 + 12);
  const float wj0[4] = {w0.x, w0.y, w0.z, w0.w};
  const float wj1[4] = {w1.x, w1.y, w1.z, w1.w};
  const float wj2[4] = {w2.x, w2.y, w2.z, w2.w};
  const float wj3[4] = {w3.x, w3.y, w3.z, w3.w};
  float4 acc = make_float4(0.f, 0.f, 0.f, 0.f);
#pragma unroll
  for (int j = 0; j < 4; j++) {
    const int tt = t - 3 + j;
    if (tt < 0) continue;
    const float m = mask[tt];
    const ushort4 xb = *(const ushort4*)(qkvz + (size_t)tt * CQKVZ + c4);
    acc.x += bf2f(xb.x) * m * wj0[j];
    acc.y += bf2f(xb.y) * m * wj1[j];
    acc.z += bf2f(xb.z) * m * wj2[j];
    acc.w += bf2f(xb.w) * m * wj3[j];
  }
  acc.x = siluf(acc.x); acc.y = siluf(acc.y); acc.z = siluf(acc.z); acc.w = siluf(acc.w);
  *(float4*)(mixed + (size_t)t * CQKV + c4) = acc;
}

// ---------------- l2norm over Dk=128 for q,k heads (in place, fp32) ----------------
__global__ __launch_bounds__(256) void l2norm_kernel(float* __restrict__ mixed) {
  const int r = blockIdx.x * 4 + (threadIdx.x >> 6);
  const int lane = threadIdx.x & 63;
  const int t = r >> 5;
  const int hh = r & 31;
  float* p = mixed + (size_t)t * CQKV + hh * 128 + lane * 2;
  float2 v = *(float2*)p;
  float s = v.x * v.x + v.y * v.y;
#pragma unroll
  for (int off = 32; off > 0; off >>= 1) s += __shfl_down(s, off);
  s = __shfl(s, 0);
  const float rn = rsqrtf(s + 1e-6f);
  v.x *= rn; v.y *= rn;
  *(float2*)p = v;
}

// ---------------- beta, g ----------------
__global__ __launch_bounds__(256) void beta_g_kernel(const float* __restrict__ ba,
                                                     const float* __restrict__ A_log,
                                                     const float* __restrict__ dt_bias,
                                                     const float* __restrict__ mask,
                                                     float* __restrict__ beta,
                                                     float* __restrict__ g) {
  const int idx = blockIdx.x * 256 + threadIdx.x;
  const int t = idx >> 4;
  const int h = idx & 15;
  const float b = ba[(size_t)t * 32 + h];
  const float a = ba[(size_t)t * 32 + 16 + h];
  const float m = mask[t];
  beta[idx] = m / (1.0f + expf(-b));
  const float xx = a + dt_bias[h];
  const float sp = (xx > 20.0f) ? xx : log1pf(expf(xx));
  g[idx] = -expf(A_log[h]) * sp * m;
}

// ---------------- per-chunk cumsum of g ----------------
__global__ __launch_bounds__(256) void gcs_kernel(const float* __restrict__ g,
                                                  float* __restrict__ gcsbuf) {
  const int idx = blockIdx.x * 256 + threadIdx.x;
  if (idx >= 1024) return;
  const int h = idx >> 6;
  const int n = idx & 63;
  const int t0 = n * 64;
  float s = 0.f;
  for (int i = 0; i < 64; i++) {
    s += g[(size_t)(t0 + i) * NH + h];
    gcsbuf[(size_t)idx * 64 + i] = s;
  }
}

// ---------------- per-chunk: A=(k_beta k^T)*decay (strict lower), attn=(q k^T)*decay*scale ----------------
__global__ __launch_bounds__(256) void pre_attn_kernel(const float* __restrict__ mixed,
                                                       const float* __restrict__ gcsbuf,
                                                       const float* __restrict__ betabuf,
                                                       float* __restrict__ abuf,
                                                       float* __restrict__ attnbuf) {
  __shared__ __align__(16) float kl[64][132];
  __shared__ float gcs_s[64];
  __shared__ float betal[64];
  const int blk = blockIdx.x;
  const int h = blk >> 6;
  const int n = blk & 63;
  const int t0 = n * 64;
  const int tid = threadIdx.x;
  if (tid < 64) {
    gcs_s[tid] = gcsbuf[(size_t)blk * 64 + tid];
    betal[tid] = betabuf[(size_t)(t0 + tid) * NH + h];
  }
#pragma unroll
  for (int rep = 0; rep < 8; rep++) {
    const int lin = rep * 256 + tid;
    const int i = lin >> 5;
    const int d = (lin & 31) * 4;
    const float4 kv = *(const float4*)(mixed + (size_t)(t0 + i) * CQKV + 2048 + h * 128 + d);
    *(float4*)&kl[i][d] = kv;
  }
  __syncthreads();
  const int cj = tid & 15;
  const int ri = tid >> 4;
  const int i0 = ri * 4, j0 = cj * 4;
  float accA[4][4], accQ[4][4];
#pragma unroll
  for (int a = 0; a < 4; a++)
#pragma unroll
    for (int b = 0; b < 4; b++) { accA[a][b] = 0.f; accQ[a][b] = 0.f; }
  const float* qbase = mixed + (size_t)t0 * CQKV + h * 128;
#pragma unroll 4
  for (int d = 0; d < 128; d++) {
    const float kj0 = kl[j0][d], kj1 = kl[j0 + 1][d], kj2 = kl[j0 + 2][d], kj3 = kl[j0 + 3][d];
#pragma unroll
    for (int a = 0; a < 4; a++) {
      const float ka = kl[i0 + a][d];
      const float qa = qbase[(size_t)(i0 + a) * CQKV + d];
      accA[a][0] += ka * kj0; accA[a][1] += ka * kj1; accA[a][2] += ka * kj2; accA[a][3] += ka * kj3;
      accQ[a][0] += qa * kj0; accQ[a][1] += qa * kj1; accQ[a][2] += qa * kj2; accQ[a][3] += qa * kj3;
    }
  }
#pragma unroll
  for (int a = 0; a < 4; a++) {
    const int i = i0 + a;
    const float gi = gcs_s[i];
    const float bi = betal[i];
    float4 Av, Qv;
    float dec;
    dec = __expf(fminf(gi - gcs_s[j0 + 0], 0.f));
    Av.x = (i > j0 + 0) ? accA[a][0] * bi * dec : 0.f;
    Qv.x = (i >= j0 + 0) ? accQ[a][0] * dec * SCALE : 0.f;
    dec = __expf(fminf(gi - gcs_s[j0 + 1], 0.f));
    Av.y = (i > j0 + 1) ? accA[a][1] * bi * dec : 0.f;
    Qv.y = (i >= j0 + 1) ? accQ[a][1] * dec * SCALE : 0.f;
    dec = __expf(fminf(gi - gcs_s[j0 + 2], 0.f));
    Av.z = (i > j0 + 2) ? accA[a][2] * bi * dec : 0.f;
    Qv.z = (i >= j0 + 2) ? accQ[a][2] * dec * SCALE : 0.f;
    dec = __expf(fminf(gi - gcs_s[j0 + 3], 0.f));
    Av.w = (i > j0 + 3) ? accA[a][3] * bi * dec : 0.f;
    Qv.w = (i >= j0 + 3) ? accQ[a][3] * dec * SCALE : 0.f;
    *(float4*)(abuf + (size_t)blk * 4096 + i * 64 + j0) = Av;
    *(float4*)(attnbuf + (size_t)blk * 4096 + i * 64 + j0) = Qv;
  }
}

// ---------------- per-chunk: T = (I+A)^-1, then T *= beta[col] ----------------
__global__ __launch_bounds__(256) void pre_solve_kernel(const float* __restrict__ abuf,
                                                        const float* __restrict__ betabuf,
                                                        float* __restrict__ tbuf) {
  __shared__ float Al[64][65];
  __shared__ float Tl[64][65];
  const int blk = blockIdx.x;
  const int h = blk >> 6;
  const int n = blk & 63;
  const int t0 = n * 64;
  const int tid = threadIdx.x;
#pragma unroll
  for (int rep = 0; rep < 4; rep++) {
    const int lin = rep * 256 + tid;
    const int i = lin >> 4;
    const int j = (lin & 15) * 4;
    const float4 av = *(const float4*)(abuf + (size_t)blk * 4096 + i * 64 + j);
    Al[i][j] = av.x; Al[i][j + 1] = av.y; Al[i][j + 2] = av.z; Al[i][j + 3] = av.w;
  }
  __syncthreads();
  if (tid < 64) {
    const int j = tid;
    const float bj = betabuf[(size_t)(t0 + j) * NH + h];
    for (int i = 0; i < 64; i++) {
      float s = (i == j) ? 1.0f : 0.0f;
      for (int l = j; l < i; l++) s -= Al[i][l] * Tl[l][j];
      Tl[i][j] = s;
    }
    for (int i = j; i < 64; i++) Tl[i][j] *= bj;
  }
  __syncthreads();
#pragma unroll
  for (int rep = 0; rep < 4; rep++) {
    const int lin = rep * 256 + tid;
    const int i = lin >> 4;
    const int j = (lin & 15) * 4;
    float4 tv;
    tv.x = Tl[i][j]; tv.y = Tl[i][j + 1]; tv.z = Tl[i][j + 2]; tv.w = Tl[i][j + 3];
    *(float4*)(tbuf + (size_t)blk * 4096 + i * 64 + j) = tv;
  }
}

// ---------------- per-chunk: u = Tb @ v ; w = Tb @ (k * e^gcs) ----------------
__global__ __launch_bounds__(256) void pre_uw_kernel(const float* __restrict__ mixed,
                                                     const float* __restrict__ tbuf,
                                                     const float* __restrict__ gcsbuf,
                                                     float* __restrict__ ubuf,
                                                     float* __restrict__ wbuf) {
  __shared__ __align__(16) float Tl[64][68];
  __shared__ __align__(16) float xl[64][132];
  __shared__ float egcs[64];
  const int blk = blockIdx.x;
  const int h = blk >> 6;
  const int n = blk & 63;
  const int t0 = n * 64;
  const int tid = threadIdx.x;
  if (tid < 64) egcs[tid] = __expf(gcsbuf[(size_t)blk * 64 + tid]);
#pragma unroll
  for (int rep = 0; rep < 4; rep++) {
    const int lin = rep * 256 + tid;
    const int i = lin >> 4;
    const int j = (lin & 15) * 4;
    const float4 tv = *(const float4*)(tbuf + (size_t)blk * 4096 + i * 64 + j);
    *(float4*)&Tl[i][j] = tv;
  }
#pragma unroll
  for (int rep = 0; rep < 8; rep++) {
    const int lin = rep * 256 + tid;
    const int i = lin >> 5;
    const int d = (lin & 31) * 4;
    const float4 vv = *(const float4*)(mixed + (size_t)(t0 + i) * CQKV + 4096 + h * 128 + d);
    *(float4*)&xl[i][d] = vv;
  }
  __syncthreads();
  const int cgu = tid & 15;
  const int riu = tid >> 4;
  const int i0 = riu * 4;
  const int d0 = cgu * 8;
  float acc[4][8];
#pragma unroll
  for (int a = 0; a < 4; a++)
#pragma unroll
    for (int b = 0; b < 8; b++) acc[a][b] = 0.f;
#pragma unroll 2
  for (int j = 0; j < 64; j++) {
    const float tv[4] = {Tl[i0][j], Tl[i0 + 1][j], Tl[i0 + 2][j], Tl[i0 + 3][j]};
    const float4 x0 = *(const float4*)&xl[j][d0];
    const float4 x1 = *(const float4*)&xl[j][d0 + 4];
    const float xv[8] = {x0.x, x0.y, x0.z, x0.w, x1.x, x1.y, x1.z, x1.w};
#pragma unroll
    for (int a = 0; a < 4; a++)
#pragma unroll
      for (int b = 0; b < 8; b++) acc[a][b] += tv[a] * xv[b];
  }
#pragma unroll
  for (int a = 0; a < 4; a++) {
    float* up = ubuf + (size_t)(t0 + i0 + a) * 2048 + h * 128 + d0;
    *(float4*)up = make_float4(acc[a][0], acc[a][1], acc[a][2], acc[a][3]);
    *(float4*)(up + 4) = make_float4(acc[a][4], acc[a][5], acc[a][6], acc[a][7]);
  }
  __syncthreads();
#pragma unroll
  for (int rep = 0; rep < 8; rep++) {
    const int lin = rep * 256 + tid;
    const int i = lin >> 5;
    const int d = (lin & 31) * 4;
    float4 kv = *(const float4*)(mixed + (size_t)(t0 + i) * CQKV + 2048 + h * 128 + d);
    const float e = egcs[i];
    kv.x *= e; kv.y *= e; kv.z *= e; kv.w *= e;
    *(float4*)&xl[i][d] = kv;
  }
  __syncthreads();
#pragma unroll
  for (int a = 0; a < 4; a++)
#pragma unroll
    for (int b = 0; b < 8; b++) acc[a][b] = 0.f;
#pragma unroll 2
  for (int j = 0; j < 64; j++) {
    const float tv[4] = {Tl[i0][j], Tl[i0 + 1][j], Tl[i0 + 2][j], Tl[i0 + 3][j]};
    const float4 x0 = *(const float4*)&xl[j][d0];
    const float4 x1 = *(const float4*)&xl[j][d0 + 4];
    const float xv[8] = {x0.x, x0.y, x0.z, x0.w, x1.x, x1.y, x1.z, x1.w};
#pragma unroll
    for (int a = 0; a < 4; a++)
#pragma unroll
      for (int b = 0; b < 8; b++) acc[a][b] += tv[a] * xv[b];
  }
#pragma unroll
  for (int a = 0; a < 4; a++) {
    float* wp = wbuf + (size_t)(t0 + i0 + a) * 2048 + h * 128 + d0;
    *(float4*)wp = make_float4(acc[a][0], acc[a][1], acc[a][2], acc[a][3]);
    *(float4*)(wp + 4) = make_float4(acc[a][4], acc[a][5], acc[a][6], acc[a][7]);
  }
}

// ---------------- sequential chunk scan; grid = 16 heads x 4 col-slices ----------------
__global__ __launch_bounds__(512) void seq_kernel(const float* __restrict__ mixed,
                                                  const float* __restrict__ ubuf,
                                                  const float* __restrict__ wbuf,
                                                  const float* __restrict__ attnbuf,
                                                  const float* __restrict__ gcsbuf,
                                                  float* __restrict__ obuf) {
  __shared__ __align__(16) float S[128][36];
  __shared__ __align__(16) float vn[64][36];
  __shared__ float wl[64][129];
  __shared__ float gcs_s[64];
  __shared__ float egq[64];
  __shared__ float edk[64];
  const int h = blockIdx.x >> 2;
  const int sl = blockIdx.x & 3;
  const int jb = sl * 32;
  const int tid = threadIdx.x;
  const int cg = tid & 7;
  const int iv = tid >> 3;
  for (int lin = tid; lin < 128 * 32; lin += 512) S[lin >> 5][lin & 31] = 0.0f;
  for (int n = 0; n < 64; n++) {
    const int t0 = n * 64;
    const int blk = h * 64 + n;
    __syncthreads();
    if (tid < 64) gcs_s[tid] = gcsbuf[(size_t)blk * 64 + tid];
    __syncthreads();
    if (tid < 64) {
      const float glast = gcs_s[63];
      egq[tid] = __expf(gcs_s[tid]) * SCALE;
      edk[tid] = __expf(glast - gcs_s[tid]);
    }
#pragma unroll
    for (int rep = 0; rep < 4; rep++) {
      const int lin = rep * 512 + tid;
      const int i = lin >> 5;
      const int d = (lin & 31) * 4;
      const float4 wv = *(const float4*)(wbuf + (size_t)(t0 + i) * 2048 + h * 128 + d);
      wl[i][d] = wv.x; wl[i][d + 1] = wv.y; wl[i][d + 2] = wv.z; wl[i][d + 3] = wv.w;
    }
    __syncthreads();
    // v_new = u - w @ S
    {
      float4 acc = *(const float4*)(ubuf + (size_t)(t0 + iv) * 2048 + h * 128 + jb + cg * 4);
#pragma unroll 8
      for (int k = 0; k < 128; k++) {
        const float wv = wl[iv][k];
        const float4 sv = *(const float4*)&S[k][cg * 4];
        acc.x -= wv * sv.x; acc.y -= wv * sv.y; acc.z -= wv * sv.z; acc.w -= wv * sv.w;
      }
      *(float4*)&vn[iv][cg * 4] = acc;
    }
    __syncthreads();
    // o = (q * scale * e^gcs) @ S + attn @ v_new
    {
      float4 acc = make_float4(0.f, 0.f, 0.f, 0.f);
      const float* qrow = mixed + (size_t)(t0 + iv) * CQKV + h * 128;
      const float eq = egq[iv];
#pragma unroll 8
      for (int k = 0; k < 128; k++) {
        const float qv = qrow[k] * eq;
        const float4 sv = *(const float4*)&S[k][cg * 4];
        acc.x += qv * sv.x; acc.y += qv * sv.y; acc.z += qv * sv.z; acc.w += qv * sv.w;
      }
      const float* arow = attnbuf + (size_t)blk * 4096 + iv * 64;
#pragma unroll 8
      for (int l = 0; l < 64; l++) {
        const float av = arow[l];
        const float4 vv = *(const float4*)&vn[l][cg * 4];
        acc.x += av * vv.x; acc.y += av * vv.y; acc.z += av * vv.z; acc.w += av * vv.w;
      }
      *(float4*)(obuf + (size_t)(t0 + iv) * 2048 + h * 128 + jb + cg * 4) = acc;
    }
    // S = S * e^glast + kdec^T @ v_new
    float a00 = 0.f, a01 = 0.f, a02 = 0.f, a03 = 0.f;
    float a10 = 0.f, a11 = 0.f, a12 = 0.f, a13 = 0.f;
#pragma unroll 4
    for (int l = 0; l < 64; l++) {
      const float* krow = mixed + (size_t)(t0 + l) * CQKV + 2048 + h * 128;
      const float ed = edk[l];
      const float k0 = krow[iv] * ed;
      const float k1 = krow[iv + 64] * ed;
      const float4 vv = *(const float4*)&vn[l][cg * 4];
      a00 += k0 * vv.x; a01 += k0 * vv.y; a02 += k0 * vv.z; a03 += k0 * vv.w;
      a10 += k1 * vv.x; a11 += k1 * vv.y; a12 += k1 * vv.z; a13 += k1 * vv.w;
    }
    const float eglast = __expf(gcs_s[63]);
    __syncthreads();
    {
      float4 s0 = *(const float4*)&S[iv][cg * 4];
      s0.x = s0.x * eglast + a00; s0.y = s0.y * eglast + a01;
      s0.z = s0.z * eglast + a02; s0.w = s0.w * eglast + a03;
      *(float4*)&S[iv][cg * 4] = s0;
      float4 s1 = *(const float4*)&S[iv + 64][cg * 4];
      s1.x = s1.x * eglast + a10; s1.y = s1.y * eglast + a11;
      s1.z = s1.z * eglast + a12; s1.w = s1.w * eglast + a13;
      *(float4*)&S[iv + 64][cg * 4] = s1;
    }
  }
}

// ---------------- gated RMSNorm over Dv=128: ob = bf16(rms(o)*w*silu(z)) ----------------
__global__ __launch_bounds__(256) void onorm_kernel(const float* __restrict__ o,
                                                    const unsigned short* __restrict__ z,
                                                    const float* __restrict__ w,
                                                    unsigned short* __restrict__ ob) {
  const int r = blockIdx.x * 4 + (threadIdx.x >> 6);  // r = t*16 + h
  const int lane = threadIdx.x & 63;
  const int t = r >> 4;
  const int h = r & 15;
  const size_t base = (size_t)t * 2048 + h * 128 + lane * 2;
  float2 v = *(const float2*)(o + base);
  float s = v.x * v.x + v.y * v.y;
#pragma unroll
  for (int off = 32; off > 0; off >>= 1) s += __shfl_down(s, off);
  s = __shfl(s, 0);
  const float rn = rsqrtf(s * (1.0f / 128.0f) + 1e-5f);
  const float2 wv = *(const float2*)(w + lane * 2);
  const ushort2 zv = *(const ushort2*)(z + base);
  ushort2 res;
  res.x = f2bf(v.x * rn * wv.x * siluf(bf2f(zv.x)));
  res.y = f2bf(v.y * rn * wv.y * siluf(bf2f(zv.y)));
  *(ushort2*)(ob + base) = res;
}

// ---------------- helpers ----------------
__global__ __launch_bounds__(256) void copy_kernel(const float* __restrict__ in,
                                                   float* __restrict__ out) {
  const int i = blockIdx.x * 256 + threadIdx.x;
  ((float4*)out)[i] = ((const float4*)in)[i];
}

extern "C" void kernel_launch(void* const* d_in, const int* in_sizes, int n_in,
                              void* d_out, int out_size, void* d_ws, size_t ws_size,
                              hipStream_t stream) {
  (void)in_sizes; (void)n_in; (void)out_size;
  const float* x        = (const float*)d_in[0];
  const float* mask     = (const float*)d_in[1];
  const float* ln1_w    = (const float*)d_in[2];
  const float* qkvz_w   = (const float*)d_in[3];
  const float* ba_w     = (const float*)d_in[4];
  const float* conv_w   = (const float*)d_in[5];
  const float* A_log    = (const float*)d_in[6];
  const float* dt_bias  = (const float*)d_in[7];
  const float* o_norm_w = (const float*)d_in[8];
  const float* out_w    = (const float*)d_in[9];
  const float* ln2_w    = (const float*)d_in[10];
  const float* gate_w   = (const float*)d_in[11];
  const float* up_w     = (const float*)d_in[12];
  const float* down_w   = (const float*)d_in[13];
  float* out = (float*)d_out;

  // ---- workspace layout (float slots), liveness-aliased; NEED unchanged from passing round ----
  const size_t NEED_BYTES = (size_t)75825152 * 4;
  if (ws_size < NEED_BYTES) return;

  float* ws = (float*)d_ws;
  // [0, 25165824): mixed_f32 (phase A)  ->  Wg/Wu/Wd bf16 (MLP phase)
  float* mixed_buf = ws;
  unsigned short* Wg = (unsigned short*)ws;                         // 16.8M elems
  unsigned short* Wu = (unsigned short*)(ws + 8388608);             // 16.8M elems
  unsigned short* Wd = (unsigned short*)(ws + 16777216);            // 16.8M elems
  // [25165824, 41943040): qkvz_bf16 -> u/w f32 -> gate/comb bf16
  unsigned short* qkvz_bf = (unsigned short*)(ws + 25165824);       // 33.5M elems
  float* u_buf = ws + 25165824;                                     // 8,388,608 f
  float* w_buf = ws + 33554432;                                     // 8,388,608 f
  unsigned short* gate_bf = (unsigned short*)(ws + 25165824);       // 33.5M elems
  // [41943040, 46137344): z bf16
  unsigned short* z_bf = (unsigned short*)(ws + 41943040);          // 8.4M elems
  // [46137344, 54525952): h_f32 -> a/t -> o_f32
  float* h_buf = ws + 46137344;
  float* a_buf = ws + 46137344;                                     // 4,194,304 f
  float* t_buf = ws + 50331648;                                     // 4,194,304 f
  float* o_buf = ws + 46137344;                                     // 8,388,608 f
  // [54525952, 58720256): h_bf16 -> o_bf16 -> h2_bf16
  unsigned short* h_bf  = (unsigned short*)(ws + 54525952);         // 8.4M elems
  unsigned short* o_bf  = (unsigned short*)(ws + 54525952);
  unsigned short* h2_bf = (unsigned short*)(ws + 54525952);
  // [58720256, 62914560): attn f32
  float* attn_buf = ws + 58720256;
  // [62914560, 71303168): Wq bf16 (16.8M elems)
  unsigned short* Wq = (unsigned short*)(ws + 62914560);
  // [71303168, 73400320): Wo bf16 (4.2M elems)
  unsigned short* Wo = (unsigned short*)(ws + 71303168);
  // smalls
  float* ba_buf   = ws + 73400320;   // 131,072
  float* beta_buf = ws + 73531392;   // 65,536
  float* g_buf    = ws + 73596928;   // 65,536
  float* gcs_buf  = ws + 73662464;   // 65,536

  // h = rms(x, ln1_w): fp32 (for ba) + bf16 (for GEMM)
  rmsnorm_kernel<1><<<4096, 256, 0, stream>>>(x, ln1_w, h_buf, h_bf);
  // weight converts needed early
  f2b_kernel<<<8192, 256, 0, stream>>>(qkvz_w, Wq);
  // qkvz = h @ qkvz_w^T  (bf16 out)
  gemm_bf16_kernel<0><<<dim3(64, 32), 256, 0, stream>>>(h_bf, Wq, nullptr, qkvz_bf, 4096, 8192, 2048);
  // ba = h @ ba_w^T
  ba_gemm_kernel<<<4096, 256, 0, stream>>>(h_buf, ba_w, ba_buf);
  // stash z columns
  zcopy_kernel<<<4096, 256, 0, stream>>>(qkvz_bf, z_bf);
  // mixed = silu(causal_conv(concat(q,k,v)*mask))  (fp32)
  conv_silu_kernel<<<24576, 256, 0, stream>>>(qkvz_bf, conv_w, mask, mixed_buf);
  // l2norm q,k heads in place
  l2norm_kernel<<<32768, 256, 0, stream>>>(mixed_buf);
  // beta, g, per-chunk cumulative decay
  beta_g_kernel<<<256, 256, 0, stream>>>(ba_buf, A_log, dt_bias, mask, beta_buf, g_buf);
  gcs_kernel<<<4, 256, 0, stream>>>(g_buf, gcs_buf);
  // delta-rule precompute
  pre_attn_kernel<<<1024, 256, 0, stream>>>(mixed_buf, gcs_buf, beta_buf, a_buf, attn_buf);
  pre_solve_kernel<<<1024, 256, 0, stream>>>(a_buf, beta_buf, t_buf);
  pre_uw_kernel<<<1024, 256, 0, stream>>>(mixed_buf, t_buf, gcs_buf, u_buf, w_buf);
  // sequential scan (o overlays dead a/t)
  seq_kernel<<<64, 512, 0, stream>>>(mixed_buf, u_buf, w_buf, attn_buf, gcs_buf, o_buf);
  // late-phase weight converts (mixed/u/w regions about to be reused are still intact;
  // Wg/Wu/Wd overlay mixed which is dead after seq)
  f2b_kernel<<<8192, 256, 0, stream>>>(gate_w, Wg);
  f2b_kernel<<<8192, 256, 0, stream>>>(up_w, Wu);
  f2b_kernel<<<8192, 256, 0, stream>>>(down_w, Wd);
  f2b_kernel<<<2048, 256, 0, stream>>>(out_w, Wo);
  // gated rmsnorm with z -> o_bf16
  onorm_kernel<<<16384, 256, 0, stream>>>(o_buf, z_bf, o_norm_w, o_bf);
  // x_mid = x + o @ out_w^T  (into d_out)
  copy_kernel<<<8192, 256, 0, stream>>>(x, out);
  gemm_bf16_kernel<1><<<dim3(16, 32), 256, 0, stream>>>(o_bf, Wo, out, nullptr, 4096, 2048, 2048);
  // h2 = rms(x_mid, ln2_w) -> bf16 only (overlays dead o_bf16)
  rmsnorm_kernel<2><<<4096, 256, 0, stream>>>(out, ln2_w, nullptr, h2_bf);
  // mlp: gate (bf16) -> silu-fused up (bf16, in place) -> down (fp32 accum into d_out)
  gemm_bf16_kernel<0><<<dim3(64, 32), 256, 0, stream>>>(h2_bf, Wg, nullptr, gate_bf, 4096, 8192, 2048);
  gemm_bf16_kernel<2><<<dim3(64, 32), 256, 0, stream>>>(h2_bf, Wu, nullptr, gate_bf, 4096, 8192, 2048);
  gemm_bf16_kernel<1><<<dim3(16, 32), 256, 0, stream>>>(gate_bf, Wd, out, nullptr, 4096, 2048, 8192);
}

// Round 4
// 2160.684 us; speedup vs baseline: 4.1643x; 1.3082x over previous
//
#include <hip/hip_runtime.h>
#include <math.h>

#define T_LEN 4096
#define DMODEL 2048
#define NH 16
#define CQKV 6144
#define CQKVZ 8192
#define SCALE 0.08838834764831845f   // 128^-0.5

using bf16x8 = __attribute__((ext_vector_type(8))) short;
using f32x4  = __attribute__((ext_vector_type(4))) float;

__device__ __forceinline__ float siluf(float x) { return x / (1.0f + __expf(-x)); }

__device__ __forceinline__ unsigned short f2bf(float f) {  // RNE
  unsigned int u = __float_as_uint(f);
  u = (u + 0x7FFFu + ((u >> 16) & 1u)) >> 16;
  return (unsigned short)u;
}
__device__ __forceinline__ float bf2f(unsigned short u) {
  return __uint_as_float(((unsigned int)u) << 16);
}
__device__ __forceinline__ ushort4 pack4(float a, float b, float c, float d) {
  ushort4 r; r.x = f2bf(a); r.y = f2bf(b); r.z = f2bf(c); r.w = f2bf(d); return r;
}

// ---------------- RMSNorm over D=2048; MODE: 1 = f32+bf16, 2 = bf16 only ----------------
template<int MODE>
__global__ __launch_bounds__(256) void rmsnorm_kernel(const float* __restrict__ x,
                                                      const float* __restrict__ w,
                                                      float* __restrict__ outf,
                                                      unsigned short* __restrict__ outb) {
  const int t = blockIdx.x;
  const int tid = threadIdx.x;
  const float4* xr = (const float4*)(x + (size_t)t * DMODEL);
  float4 v0 = xr[tid];
  float4 v1 = xr[tid + 256];
  float s = v0.x*v0.x + v0.y*v0.y + v0.z*v0.z + v0.w*v0.w
          + v1.x*v1.x + v1.y*v1.y + v1.z*v1.z + v1.w*v1.w;
#pragma unroll
  for (int off = 32; off > 0; off >>= 1) s += __shfl_down(s, off);
  __shared__ float red[4];
  if ((tid & 63) == 0) red[tid >> 6] = s;
  __syncthreads();
  const float tot = red[0] + red[1] + red[2] + red[3];
  const float r = rsqrtf(tot * (1.0f / DMODEL) + 1e-5f);
  const float4* wr = (const float4*)w;
  const float4 w0 = wr[tid], w1 = wr[tid + 256];
  float4 o0, o1;
  o0.x = v0.x*r*w0.x; o0.y = v0.y*r*w0.y; o0.z = v0.z*r*w0.z; o0.w = v0.w*r*w0.w;
  o1.x = v1.x*r*w1.x; o1.y = v1.y*r*w1.y; o1.z = v1.z*r*w1.z; o1.w = v1.w*r*w1.w;
  if (MODE == 1) {
    float4* orow = (float4*)(outf + (size_t)t * DMODEL);
    orow[tid] = o0;
    orow[tid + 256] = o1;
  }
  ushort4* brow = (ushort4*)(outb + (size_t)t * DMODEL);
  brow[tid] = pack4(o0.x, o0.y, o0.z, o0.w);
  brow[tid + 256] = pack4(o1.x, o1.y, o1.z, o1.w);
}

// ---------------- fp32 -> bf16 bulk convert ----------------
__global__ __launch_bounds__(256) void f2b_kernel(const float* __restrict__ in,
                                                  unsigned short* __restrict__ out) {
  const size_t i = (size_t)blockIdx.x * 256 + threadIdx.x;
  const float4 a = ((const float4*)in)[2 * i];
  const float4 b = ((const float4*)in)[2 * i + 1];
  ((ushort4*)out)[2 * i] = pack4(a.x, a.y, a.z, a.w);
  ((ushort4*)out)[2 * i + 1] = pack4(b.x, b.y, b.z, b.w);
}

// ---------------- bf16 MFMA GEMM: C[M][N] = A[M][K] * B[N][K]^T ----------------
// EPI: 0 = bf16 store, 1 = fp32 accumulate, 2 = silu(gate)*acc -> bf16 in place
template<int EPI>
__global__ __launch_bounds__(256) void gemm_bf16_kernel(const unsigned short* __restrict__ A,
                                                        const unsigned short* __restrict__ B,
                                                        float* __restrict__ Cf,
                                                        unsigned short* __restrict__ Cb,
                                                        int M, int N, int K) {
  __shared__ __align__(16) unsigned short As[128 * 40];
  __shared__ __align__(16) unsigned short Bs[128 * 40];
  const int bm = blockIdx.y * 128;
  const int bn = blockIdx.x * 128;
  const int tid = threadIdx.x;
  const int row = tid >> 1;
  const int co  = (tid & 1) * 16;
  const unsigned short* Ag = A + (size_t)(bm + row) * K + co;
  const unsigned short* Bg = B + (size_t)(bn + row) * K + co;
  unsigned short* Asw = &As[row * 40 + co];
  unsigned short* Bsw = &Bs[row * 40 + co];
  const int wv = tid >> 6;
  const int ln = tid & 63;
  const int mo = (wv >> 1) * 64;
  const int no = (wv & 1) * 64;
  const int fr = ln & 15;
  const int q8 = (ln >> 4) * 8;

  f32x4 acc[4][4];
  const f32x4 zero = {0.f, 0.f, 0.f, 0.f};
#pragma unroll
  for (int mi = 0; mi < 4; mi++)
#pragma unroll
    for (int ni = 0; ni < 4; ni++) acc[mi][ni] = zero;

  for (int k0 = 0; k0 < K; k0 += 32) {
    const uint4 av0 = *(const uint4*)(Ag + k0);
    const uint4 av1 = *(const uint4*)(Ag + k0 + 8);
    const uint4 bv0 = *(const uint4*)(Bg + k0);
    const uint4 bv1 = *(const uint4*)(Bg + k0 + 8);
    __syncthreads();
    *(uint4*)Asw = av0; *(uint4*)(Asw + 8) = av1;
    *(uint4*)Bsw = bv0; *(uint4*)(Bsw + 8) = bv1;
    __syncthreads();
    bf16x8 afr[4], bfr[4];
#pragma unroll
    for (int mi = 0; mi < 4; mi++)
      afr[mi] = *(const bf16x8*)&As[(mo + mi * 16 + fr) * 40 + q8];
#pragma unroll
    for (int ni = 0; ni < 4; ni++)
      bfr[ni] = *(const bf16x8*)&Bs[(no + ni * 16 + fr) * 40 + q8];
#pragma unroll
    for (int mi = 0; mi < 4; mi++)
#pragma unroll
      for (int ni = 0; ni < 4; ni++)
        acc[mi][ni] = __builtin_amdgcn_mfma_f32_16x16x32_bf16(afr[mi], bfr[ni], acc[mi][ni], 0, 0, 0);
  }

  const int cm = (ln >> 4) * 4;
  const int cn = fr;
#pragma unroll
  for (int mi = 0; mi < 4; mi++) {
#pragma unroll
    for (int ni = 0; ni < 4; ni++) {
#pragma unroll
      for (int r = 0; r < 4; r++) {
        const int grow = bm + mo + mi * 16 + cm + r;
        const int gcol = bn + no + ni * 16 + cn;
        const size_t off = (size_t)grow * N + gcol;
        const float v = acc[mi][ni][r];
        if (EPI == 0) {
          Cb[off] = f2bf(v);
        } else if (EPI == 1) {
          Cf[off] += v;
        } else {
          Cb[off] = f2bf(siluf(bf2f(Cb[off])) * v);
        }
      }
    }
  }
}

// ---------------- ba = h @ ba_w^T ----------------
__global__ __launch_bounds__(256) void ba_gemm_kernel(const float* __restrict__ h_in,
                                                      const float* __restrict__ ba_w,
                                                      float* __restrict__ ba_out) {
  __shared__ __align__(16) float hl[2048];
  __shared__ float red[32][9];
  const int t = blockIdx.x;
  const int tid = threadIdx.x;
  const float4* hr = (const float4*)(h_in + (size_t)t * DMODEL);
  ((float4*)hl)[tid] = hr[tid];
  ((float4*)hl)[tid + 256] = hr[tid + 256];
  __syncthreads();
  const int c = tid & 31;
  const int p = tid >> 5;
  const float* wrow = ba_w + (size_t)c * DMODEL + p * 256;
  const float* hrow = hl + p * 256;
  float s = 0.f;
#pragma unroll 8
  for (int k = 0; k < 256; k++) s += hrow[k] * wrow[k];
  red[c][p] = s;
  __syncthreads();
  if (tid < 32) {
    float tot = 0.f;
#pragma unroll
    for (int q = 0; q < 8; q++) tot += red[tid][q];
    ba_out[(size_t)t * 32 + tid] = tot;
  }
}

// ---------------- extract z columns from bf16 qkvz ----------------
__global__ __launch_bounds__(256) void zcopy_kernel(const unsigned short* __restrict__ qkvz,
                                                    unsigned short* __restrict__ z) {
  const int idx = blockIdx.x * 256 + threadIdx.x;
  const int t = idx >> 8;
  const int c8 = (idx & 255) * 8;
  *(uint4*)(z + (size_t)t * 2048 + c8) =
      *(const uint4*)(qkvz + (size_t)t * CQKVZ + CQKV + c8);
}

// ---------------- causal depthwise conv (K=4) + SiLU; bf16 in, fp32 out ----------------
__global__ __launch_bounds__(256) void conv_silu_kernel(const unsigned short* __restrict__ qkvz,
                                                        const float* __restrict__ conv_w,
                                                        const float* __restrict__ mask,
                                                        float* __restrict__ mixed) {
  const int idx = blockIdx.x * 256 + threadIdx.x;
  const int c4 = (idx % 1536) * 4;
  const int t = idx / 1536;
  const float4 w0 = *(const float4*)(conv_w + (size_t)c4 * 4);
  const float4 w1 = *(const float4*)(conv_w + (size_t)c4 * 4 + 4);
  const float4 w2 = *(const float4*)(conv_w + (size_t)c4 * 4 + 8);
  const float4 w3 = *(const float4*)(conv_w + (size_t)c4 * 4 + 12);
  const float wj0[4] = {w0.x, w0.y, w0.z, w0.w};
  const float wj1[4] = {w1.x, w1.y, w1.z, w1.w};
  const float wj2[4] = {w2.x, w2.y, w2.z, w2.w};
  const float wj3[4] = {w3.x, w3.y, w3.z, w3.w};
  float4 acc = make_float4(0.f, 0.f, 0.f, 0.f);
#pragma unroll
  for (int j = 0; j < 4; j++) {
    const int tt = t - 3 + j;
    if (tt < 0) continue;
    const float m = mask[tt];
    const ushort4 xb = *(const ushort4*)(qkvz + (size_t)tt * CQKVZ + c4);
    acc.x += bf2f(xb.x) * m * wj0[j];
    acc.y += bf2f(xb.y) * m * wj1[j];
    acc.z += bf2f(xb.z) * m * wj2[j];
    acc.w += bf2f(xb.w) * m * wj3[j];
  }
  acc.x = siluf(acc.x); acc.y = siluf(acc.y); acc.z = siluf(acc.z); acc.w = siluf(acc.w);
  *(float4*)(mixed + (size_t)t * CQKV + c4) = acc;
}

// ---------------- l2norm over Dk=128 for q,k heads (in place, fp32) ----------------
__global__ __launch_bounds__(256) void l2norm_kernel(float* __restrict__ mixed) {
  const int r = blockIdx.x * 4 + (threadIdx.x >> 6);
  const int lane = threadIdx.x & 63;
  const int t = r >> 5;
  const int hh = r & 31;
  float* p = mixed + (size_t)t * CQKV + hh * 128 + lane * 2;
  float2 v = *(float2*)p;
  float s = v.x * v.x + v.y * v.y;
#pragma unroll
  for (int off = 32; off > 0; off >>= 1) s += __shfl_down(s, off);
  s = __shfl(s, 0);
  const float rn = rsqrtf(s + 1e-6f);
  v.x *= rn; v.y *= rn;
  *(float2*)p = v;
}

// ---------------- beta, g ----------------
__global__ __launch_bounds__(256) void beta_g_kernel(const float* __restrict__ ba,
                                                     const float* __restrict__ A_log,
                                                     const float* __restrict__ dt_bias,
                                                     const float* __restrict__ mask,
                                                     float* __restrict__ beta,
                                                     float* __restrict__ g) {
  const int idx = blockIdx.x * 256 + threadIdx.x;
  const int t = idx >> 4;
  const int h = idx & 15;
  const float b = ba[(size_t)t * 32 + h];
  const float a = ba[(size_t)t * 32 + 16 + h];
  const float m = mask[t];
  beta[idx] = m / (1.0f + expf(-b));
  const float xx = a + dt_bias[h];
  const float sp = (xx > 20.0f) ? xx : log1pf(expf(xx));
  g[idx] = -expf(A_log[h]) * sp * m;
}

// ---------------- per-chunk cumsum of g + decay factors ----------------
__global__ __launch_bounds__(256) void gcs_kernel(const float* __restrict__ g,
                                                  float* __restrict__ gcsbuf,
                                                  float* __restrict__ edkbuf,
                                                  float* __restrict__ egqbuf,
                                                  float* __restrict__ adecbuf) {
  const int idx = blockIdx.x * 256 + threadIdx.x;  // chunk id = h*64 + n
  if (idx >= 1024) return;
  const int h = idx >> 6;
  const int n = idx & 63;
  const int t0 = n * 64;
  float s = 0.f;
  for (int i = 0; i < 64; i++) {
    s += g[(size_t)(t0 + i) * NH + h];
    gcsbuf[(size_t)idx * 64 + i] = s;
  }
  const float glast = s;
  adecbuf[idx] = __expf(glast);
  for (int i = 0; i < 64; i++) {
    const float gi = gcsbuf[(size_t)idx * 64 + i];
    edkbuf[(size_t)idx * 64 + i] = __expf(glast - gi);
    egqbuf[(size_t)idx * 64 + i] = __expf(gi) * SCALE;
  }
}

// ---------------- per-chunk: A=(k_beta k^T)*decay (strict lower), attn=(q k^T)*decay*scale ----------------
__global__ __launch_bounds__(256) void pre_attn_kernel(const float* __restrict__ mixed,
                                                       const float* __restrict__ gcsbuf,
                                                       const float* __restrict__ betabuf,
                                                       float* __restrict__ abuf,
                                                       float* __restrict__ attnbuf) {
  __shared__ __align__(16) float kl[64][132];
  __shared__ float gcs_s[64];
  __shared__ float betal[64];
  const int blk = blockIdx.x;
  const int h = blk >> 6;
  const int n = blk & 63;
  const int t0 = n * 64;
  const int tid = threadIdx.x;
  if (tid < 64) {
    gcs_s[tid] = gcsbuf[(size_t)blk * 64 + tid];
    betal[tid] = betabuf[(size_t)(t0 + tid) * NH + h];
  }
#pragma unroll
  for (int rep = 0; rep < 8; rep++) {
    const int lin = rep * 256 + tid;
    const int i = lin >> 5;
    const int d = (lin & 31) * 4;
    const float4 kv = *(const float4*)(mixed + (size_t)(t0 + i) * CQKV + 2048 + h * 128 + d);
    *(float4*)&kl[i][d] = kv;
  }
  __syncthreads();
  const int cj = tid & 15;
  const int ri = tid >> 4;
  const int i0 = ri * 4, j0 = cj * 4;
  float accA[4][4], accQ[4][4];
#pragma unroll
  for (int a = 0; a < 4; a++)
#pragma unroll
    for (int b = 0; b < 4; b++) { accA[a][b] = 0.f; accQ[a][b] = 0.f; }
  const float* qbase = mixed + (size_t)t0 * CQKV + h * 128;
#pragma unroll 4
  for (int d = 0; d < 128; d++) {
    const float kj0 = kl[j0][d], kj1 = kl[j0 + 1][d], kj2 = kl[j0 + 2][d], kj3 = kl[j0 + 3][d];
#pragma unroll
    for (int a = 0; a < 4; a++) {
      const float ka = kl[i0 + a][d];
      const float qa = qbase[(size_t)(i0 + a) * CQKV + d];
      accA[a][0] += ka * kj0; accA[a][1] += ka * kj1; accA[a][2] += ka * kj2; accA[a][3] += ka * kj3;
      accQ[a][0] += qa * kj0; accQ[a][1] += qa * kj1; accQ[a][2] += qa * kj2; accQ[a][3] += qa * kj3;
    }
  }
#pragma unroll
  for (int a = 0; a < 4; a++) {
    const int i = i0 + a;
    const float gi = gcs_s[i];
    const float bi = betal[i];
    float4 Av, Qv;
    float dec;
    dec = __expf(fminf(gi - gcs_s[j0 + 0], 0.f));
    Av.x = (i > j0 + 0) ? accA[a][0] * bi * dec : 0.f;
    Qv.x = (i >= j0 + 0) ? accQ[a][0] * dec * SCALE : 0.f;
    dec = __expf(fminf(gi - gcs_s[j0 + 1], 0.f));
    Av.y = (i > j0 + 1) ? accA[a][1] * bi * dec : 0.f;
    Qv.y = (i >= j0 + 1) ? accQ[a][1] * dec * SCALE : 0.f;
    dec = __expf(fminf(gi - gcs_s[j0 + 2], 0.f));
    Av.z = (i > j0 + 2) ? accA[a][2] * bi * dec : 0.f;
    Qv.z = (i >= j0 + 2) ? accQ[a][2] * dec * SCALE : 0.f;
    dec = __expf(fminf(gi - gcs_s[j0 + 3], 0.f));
    Av.w = (i > j0 + 3) ? accA[a][3] * bi * dec : 0.f;
    Qv.w = (i >= j0 + 3) ? accQ[a][3] * dec * SCALE : 0.f;
    *(float4*)(abuf + (size_t)blk * 4096 + i * 64 + j0) = Av;
    *(float4*)(attnbuf + (size_t)blk * 4096 + i * 64 + j0) = Qv;
  }
}

// ---------------- per-chunk: T = (I+A)^-1, then T *= beta[col] ----------------
__global__ __launch_bounds__(256) void pre_solve_kernel(const float* __restrict__ abuf,
                                                        const float* __restrict__ betabuf,
                                                        float* __restrict__ tbuf) {
  __shared__ float Al[64][65];
  __shared__ float Tl[64][65];
  const int blk = blockIdx.x;
  const int h = blk >> 6;
  const int n = blk & 63;
  const int t0 = n * 64;
  const int tid = threadIdx.x;
#pragma unroll
  for (int rep = 0; rep < 4; rep++) {
    const int lin = rep * 256 + tid;
    const int i = lin >> 4;
    const int j = (lin & 15) * 4;
    const float4 av = *(const float4*)(abuf + (size_t)blk * 4096 + i * 64 + j);
    Al[i][j] = av.x; Al[i][j + 1] = av.y; Al[i][j + 2] = av.z; Al[i][j + 3] = av.w;
  }
  __syncthreads();
  if (tid < 64) {
    const int j = tid;
    const float bj = betabuf[(size_t)(t0 + j) * NH + h];
    for (int i = 0; i < 64; i++) {
      float s = (i == j) ? 1.0f : 0.0f;
      for (int l = j; l < i; l++) s -= Al[i][l] * Tl[l][j];
      Tl[i][j] = s;
    }
    for (int i = j; i < 64; i++) Tl[i][j] *= bj;
  }
  __syncthreads();
#pragma unroll
  for (int rep = 0; rep < 4; rep++) {
    const int lin = rep * 256 + tid;
    const int i = lin >> 4;
    const int j = (lin & 15) * 4;
    float4 tv;
    tv.x = Tl[i][j]; tv.y = Tl[i][j + 1]; tv.z = Tl[i][j + 2]; tv.w = Tl[i][j + 3];
    *(float4*)(tbuf + (size_t)blk * 4096 + i * 64 + j) = tv;
  }
}

// ---------------- per-chunk: u = Tb @ v ; w = Tb @ (k * e^gcs) ----------------
__global__ __launch_bounds__(256) void pre_uw_kernel(const float* __restrict__ mixed,
                                                     const float* __restrict__ tbuf,
                                                     const float* __restrict__ gcsbuf,
                                                     float* __restrict__ ubuf,
                                                     float* __restrict__ wbuf) {
  __shared__ __align__(16) float Tl[64][68];
  __shared__ __align__(16) float xl[64][132];
  __shared__ float egcs[64];
  const int blk = blockIdx.x;
  const int h = blk >> 6;
  const int n = blk & 63;
  const int t0 = n * 64;
  const int tid = threadIdx.x;
  if (tid < 64) egcs[tid] = __expf(gcsbuf[(size_t)blk * 64 + tid]);
#pragma unroll
  for (int rep = 0; rep < 4; rep++) {
    const int lin = rep * 256 + tid;
    const int i = lin >> 4;
    const int j = (lin & 15) * 4;
    const float4 tv = *(const float4*)(tbuf + (size_t)blk * 4096 + i * 64 + j);
    *(float4*)&Tl[i][j] = tv;
  }
#pragma unroll
  for (int rep = 0; rep < 8; rep++) {
    const int lin = rep * 256 + tid;
    const int i = lin >> 5;
    const int d = (lin & 31) * 4;
    const float4 vv = *(const float4*)(mixed + (size_t)(t0 + i) * CQKV + 4096 + h * 128 + d);
    *(float4*)&xl[i][d] = vv;
  }
  __syncthreads();
  const int cgu = tid & 15;
  const int riu = tid >> 4;
  const int i0 = riu * 4;
  const int d0 = cgu * 8;
  float acc[4][8];
#pragma unroll
  for (int a = 0; a < 4; a++)
#pragma unroll
    for (int b = 0; b < 8; b++) acc[a][b] = 0.f;
#pragma unroll 2
  for (int j = 0; j < 64; j++) {
    const float tv[4] = {Tl[i0][j], Tl[i0 + 1][j], Tl[i0 + 2][j], Tl[i0 + 3][j]};
    const float4 x0 = *(const float4*)&xl[j][d0];
    const float4 x1 = *(const float4*)&xl[j][d0 + 4];
    const float xv[8] = {x0.x, x0.y, x0.z, x0.w, x1.x, x1.y, x1.z, x1.w};
#pragma unroll
    for (int a = 0; a < 4; a++)
#pragma unroll
      for (int b = 0; b < 8; b++) acc[a][b] += tv[a] * xv[b];
  }
#pragma unroll
  for (int a = 0; a < 4; a++) {
    float* up = ubuf + (size_t)(t0 + i0 + a) * 2048 + h * 128 + d0;
    *(float4*)up = make_float4(acc[a][0], acc[a][1], acc[a][2], acc[a][3]);
    *(float4*)(up + 4) = make_float4(acc[a][4], acc[a][5], acc[a][6], acc[a][7]);
  }
  __syncthreads();
#pragma unroll
  for (int rep = 0; rep < 8; rep++) {
    const int lin = rep * 256 + tid;
    const int i = lin >> 5;
    const int d = (lin & 31) * 4;
    float4 kv = *(const float4*)(mixed + (size_t)(t0 + i) * CQKV + 2048 + h * 128 + d);
    const float e = egcs[i];
    kv.x *= e; kv.y *= e; kv.z *= e; kv.w *= e;
    *(float4*)&xl[i][d] = kv;
  }
  __syncthreads();
#pragma unroll
  for (int a = 0; a < 4; a++)
#pragma unroll
    for (int b = 0; b < 8; b++) acc[a][b] = 0.f;
#pragma unroll 2
  for (int j = 0; j < 64; j++) {
    const float tv[4] = {Tl[i0][j], Tl[i0 + 1][j], Tl[i0 + 2][j], Tl[i0 + 3][j]};
    const float4 x0 = *(const float4*)&xl[j][d0];
    const float4 x1 = *(const float4*)&xl[j][d0 + 4];
    const float xv[8] = {x0.x, x0.y, x0.z, x0.w, x1.x, x1.y, x1.z, x1.w};
#pragma unroll
    for (int a = 0; a < 4; a++)
#pragma unroll
      for (int b = 0; b < 8; b++) acc[a][b] += tv[a] * xv[b];
  }
#pragma unroll
  for (int a = 0; a < 4; a++) {
    float* wp = wbuf + (size_t)(t0 + i0 + a) * 2048 + h * 128 + d0;
    *(float4*)wp = make_float4(acc[a][0], acc[a][1], acc[a][2], acc[a][3]);
    *(float4*)(wp + 4) = make_float4(acc[a][4], acc[a][5], acc[a][6], acc[a][7]);
  }
}

// ---------------- sequential scan (minimal): v_new + S update only ----------------
// grid = 16 heads x 8 col-slices (W=16); stores S_n (bf16) and v_new (fp32, in place of u)
__global__ __launch_bounds__(256) void scan_kernel(const float* __restrict__ mixed,
                                                   float* __restrict__ ubuf,       // u in, v_new out
                                                   const float* __restrict__ wbuf,
                                                   const float* __restrict__ edkbuf,
                                                   const float* __restrict__ adecbuf,
                                                   unsigned short* __restrict__ Sbuf) {
  __shared__ unsigned short wl[64][132];   // bf16 w rows
  __shared__ unsigned short kl[64][132];   // bf16 raw k rows
  __shared__ float Ssl[128][20];           // S slice (128 x 16), fp32
  __shared__ float vns[64][20];            // v_new * edk (scaled), fp32
  __shared__ float edk_s[64];
  const int h = blockIdx.x >> 3;
  const int sl = blockIdx.x & 7;
  const int jb = sl * 16;
  const int tid = threadIdx.x;
  const int li = tid >> 2;            // load/vn row
  const int lc = (tid & 3) * 32;      // load col base (for w,k)
  const int vc = (tid & 3) * 4;       // vn col base
  const int ud = (tid & 31) * 4;      // update d0
  const int uc = (tid >> 5) * 2;      // update c0

  for (int lin = tid; lin < 128 * 16; lin += 256) Ssl[lin >> 4][lin & 15] = 0.f;

  // prefetch chunk 0
  float4 wreg[8], kreg[8], ureg;
  {
    const float* wp = wbuf + (size_t)li * 2048 + h * 128 + lc;
    const float* kp = mixed + (size_t)li * CQKV + 2048 + h * 128 + lc;
#pragma unroll
    for (int q = 0; q < 8; q++) {
      wreg[q] = *(const float4*)(wp + q * 4);
      kreg[q] = *(const float4*)(kp + q * 4);
    }
    ureg = *(const float4*)(ubuf + (size_t)li * 2048 + h * 128 + jb + vc);
  }

  for (int n = 0; n < 64; n++) {
    const int t0 = n * 64;
    const int blk = h * 64 + n;
    __syncthreads();   // protect wl/kl/vns from previous iteration's readers
    if (tid < 64) edk_s[tid] = edkbuf[(size_t)blk * 64 + tid];
    const float a = adecbuf[blk];
    // stage regs -> LDS (bf16)
#pragma unroll
    for (int q = 0; q < 8; q++) {
      *(ushort4*)&wl[li][lc + q * 4] = pack4(wreg[q].x, wreg[q].y, wreg[q].z, wreg[q].w);
      *(ushort4*)&kl[li][lc + q * 4] = pack4(kreg[q].x, kreg[q].y, kreg[q].z, kreg[q].w);
    }
    const float4 ucur = ureg;
    // prefetch chunk n+1 (overlaps with compute below)
    if (n < 63) {
      const float* wp = wbuf + (size_t)(t0 + 64 + li) * 2048 + h * 128 + lc;
      const float* kp = mixed + (size_t)(t0 + 64 + li) * CQKV + 2048 + h * 128 + lc;
#pragma unroll
      for (int q = 0; q < 8; q++) {
        wreg[q] = *(const float4*)(wp + q * 4);
        kreg[q] = *(const float4*)(kp + q * 4);
      }
      ureg = *(const float4*)(ubuf + (size_t)(t0 + 64 + li) * 2048 + h * 128 + jb + vc);
    }
    __syncthreads();   // wl/kl/edk ready
    // v_new[li][vc..vc+3] = u - w @ S
    {
      float4 acc = ucur;
#pragma unroll 8
      for (int d = 0; d < 128; d += 4) {
        const ushort4 wq = *(const ushort4*)&wl[li][d];
        const float w0 = bf2f(wq.x), w1 = bf2f(wq.y), w2 = bf2f(wq.z), w3 = bf2f(wq.w);
        const float4 s0 = *(const float4*)&Ssl[d][vc];
        const float4 s1 = *(const float4*)&Ssl[d + 1][vc];
        const float4 s2 = *(const float4*)&Ssl[d + 2][vc];
        const float4 s3 = *(const float4*)&Ssl[d + 3][vc];
        acc.x -= w0 * s0.x + w1 * s1.x + w2 * s2.x + w3 * s3.x;
        acc.y -= w0 * s0.y + w1 * s1.y + w2 * s2.y + w3 * s3.y;
        acc.z -= w0 * s0.z + w1 * s1.z + w2 * s2.z + w3 * s3.z;
        acc.w -= w0 * s0.w + w1 * s1.w + w2 * s2.w + w3 * s3.w;
      }
      // store v_new (unscaled) to global, scaled by edk to LDS
      *(float4*)(ubuf + (size_t)(t0 + li) * 2048 + h * 128 + jb + vc) = acc;
      const float ed = edk_s[li];
      float4 av; av.x = acc.x * ed; av.y = acc.y * ed; av.z = acc.z * ed; av.w = acc.w * ed;
      *(float4*)&vns[li][vc] = av;
    }
    __syncthreads();   // vns ready; all Ssl reads complete
    // S'[ud..ud+3][uc..uc+1] = a*S + kdec^T @ v_new ; store old S -> Sbuf (bf16)
    {
      float2 sold[4], acc2[4];
#pragma unroll
      for (int r = 0; r < 4; r++) {
        sold[r] = *(const float2*)&Ssl[ud + r][uc];
        acc2[r].x = a * sold[r].x;
        acc2[r].y = a * sold[r].y;
      }
#pragma unroll 8
      for (int l = 0; l < 64; l++) {
        const ushort4 kb = *(const ushort4*)&kl[l][ud];
        const float2 vv = *(const float2*)&vns[l][uc];
        const float k0 = bf2f(kb.x), k1 = bf2f(kb.y), k2 = bf2f(kb.z), k3 = bf2f(kb.w);
        acc2[0].x += k0 * vv.x; acc2[0].y += k0 * vv.y;
        acc2[1].x += k1 * vv.x; acc2[1].y += k1 * vv.y;
        acc2[2].x += k2 * vv.x; acc2[2].y += k2 * vv.y;
        acc2[3].x += k3 * vv.x; acc2[3].y += k3 * vv.y;
      }
#pragma unroll
      for (int r = 0; r < 4; r++) {
        ushort2 sb; sb.x = f2bf(sold[r].x); sb.y = f2bf(sold[r].y);
        *(ushort2*)(Sbuf + (size_t)blk * 16384 + (ud + r) * 128 + jb + uc) = sb;
        *(float2*)&Ssl[ud + r][uc] = acc2[r];
      }
    }
  }
}

// ---------------- parallel o: o = (q*egq) @ S_n + attn @ v_new ; grid = 1024 chunk-heads ----------------
__global__ __launch_bounds__(256) void ocomp_kernel(const float* __restrict__ mixed,
                                                    const unsigned short* __restrict__ Sbuf,
                                                    const float* __restrict__ vnbuf,
                                                    const float* __restrict__ attnbuf,
                                                    const float* __restrict__ egqbuf,
                                                    float* __restrict__ obuf) {
  __shared__ unsigned short Sl[128][136];  // bf16 S (then rows 0..63 reused for v_new)
  __shared__ unsigned short ql[64][136];   // bf16 q*egq
  __shared__ unsigned short al[64][72];    // bf16 attn
  const int blk = blockIdx.x;
  const int h = blk >> 6;
  const int n = blk & 63;
  const int t0 = n * 64;
  const int tid = threadIdx.x;
  // stage S (coalesced uint4 = 8 bf16)
  {
    const int d = tid >> 1;
    const int cb = (tid & 1) * 64;
    const unsigned short* Sg = Sbuf + (size_t)blk * 16384 + d * 128 + cb;
#pragma unroll
    for (int q = 0; q < 8; q++)
      *(uint4*)&Sl[d][cb + q * 8] = *(const uint4*)(Sg + q * 8);
  }
  // stage q * egq -> bf16
  {
    const int li = tid >> 2;
    const int lcq = (tid & 3) * 32;
    const float eg = egqbuf[(size_t)blk * 64 + li];
    const float* qp = mixed + (size_t)(t0 + li) * CQKV + h * 128 + lcq;
#pragma unroll
    for (int q = 0; q < 8; q++) {
      const float4 v = *(const float4*)(qp + q * 4);
      *(ushort4*)&ql[li][lcq + q * 4] = pack4(v.x * eg, v.y * eg, v.z * eg, v.w * eg);
    }
  }
  // stage attn -> bf16
  {
    const int ai = tid >> 2;
    const int ac = (tid & 3) * 16;
    const float* ap = attnbuf + (size_t)blk * 4096 + ai * 64 + ac;
#pragma unroll
    for (int q = 0; q < 4; q++) {
      const float4 v = *(const float4*)(ap + q * 4);
      *(ushort4*)&al[ai][ac + q * 4] = pack4(v.x, v.y, v.z, v.w);
    }
  }
  __syncthreads();
  const int i0 = (tid >> 4) * 4;
  const int c0 = (tid & 15) * 8;
  float acc[4][8];
#pragma unroll
  for (int a = 0; a < 4; a++)
#pragma unroll
    for (int b = 0; b < 8; b++) acc[a][b] = 0.f;
  // o1 = (q*egq) @ S
#pragma unroll 4
  for (int d = 0; d < 128; d += 4) {
    ushort4 qa[4];
#pragma unroll
    for (int a = 0; a < 4; a++) qa[a] = *(const ushort4*)&ql[i0 + a][d];
#pragma unroll
    for (int dd = 0; dd < 4; dd++) {
      const uint4 sv = *(const uint4*)&Sl[d + dd][c0];
      float sf[8];
      sf[0] = __uint_as_float(sv.x << 16); sf[1] = __uint_as_float(sv.x & 0xFFFF0000u);
      sf[2] = __uint_as_float(sv.y << 16); sf[3] = __uint_as_float(sv.y & 0xFFFF0000u);
      sf[4] = __uint_as_float(sv.z << 16); sf[5] = __uint_as_float(sv.z & 0xFFFF0000u);
      sf[6] = __uint_as_float(sv.w << 16); sf[7] = __uint_as_float(sv.w & 0xFFFF0000u);
      const float f0 = bf2f(dd == 0 ? qa[0].x : dd == 1 ? qa[0].y : dd == 2 ? qa[0].z : qa[0].w);
      const float f1 = bf2f(dd == 0 ? qa[1].x : dd == 1 ? qa[1].y : dd == 2 ? qa[1].z : qa[1].w);
      const float f2 = bf2f(dd == 0 ? qa[2].x : dd == 1 ? qa[2].y : dd == 2 ? qa[2].z : qa[2].w);
      const float f3 = bf2f(dd == 0 ? qa[3].x : dd == 1 ? qa[3].y : dd == 2 ? qa[3].z : qa[3].w);
#pragma unroll
      for (int b = 0; b < 8; b++) {
        acc[0][b] += f0 * sf[b];
        acc[1][b] += f1 * sf[b];
        acc[2][b] += f2 * sf[b];
        acc[3][b] += f3 * sf[b];
      }
    }
  }
  __syncthreads();
  // stage v_new -> bf16 into rows 0..63 of Sl
  {
    const int li = tid >> 2;
    const int lcq = (tid & 3) * 32;
    const float* vp = vnbuf + (size_t)(t0 + li) * 2048 + h * 128 + lcq;
#pragma unroll
    for (int q = 0; q < 8; q++) {
      const float4 v = *(const float4*)(vp + q * 4);
      *(ushort4*)&Sl[li][lcq + q * 4] = pack4(v.x, v.y, v.z, v.w);
    }
  }
  __syncthreads();
  // o += attn @ v_new
#pragma unroll 4
  for (int l = 0; l < 64; l += 4) {
    ushort4 aa[4];
#pragma unroll
    for (int a = 0; a < 4; a++) aa[a] = *(const ushort4*)&al[i0 + a][l];
#pragma unroll
    for (int dd = 0; dd < 4; dd++) {
      const uint4 sv = *(const uint4*)&Sl[l + dd][c0];
      float sf[8];
      sf[0] = __uint_as_float(sv.x << 16); sf[1] = __uint_as_float(sv.x & 0xFFFF0000u);
      sf[2] = __uint_as_float(sv.y << 16); sf[3] = __uint_as_float(sv.y & 0xFFFF0000u);
      sf[4] = __uint_as_float(sv.z << 16); sf[5] = __uint_as_float(sv.z & 0xFFFF0000u);
      sf[6] = __uint_as_float(sv.w << 16); sf[7] = __uint_as_float(sv.w & 0xFFFF0000u);
      const float f0 = bf2f(dd == 0 ? aa[0].x : dd == 1 ? aa[0].y : dd == 2 ? aa[0].z : aa[0].w);
      const float f1 = bf2f(dd == 0 ? aa[1].x : dd == 1 ? aa[1].y : dd == 2 ? aa[1].z : aa[1].w);
      const float f2 = bf2f(dd == 0 ? aa[2].x : dd == 1 ? aa[2].y : dd == 2 ? aa[2].z : aa[2].w);
      const float f3 = bf2f(dd == 0 ? aa[3].x : dd == 1 ? aa[3].y : dd == 2 ? aa[3].z : aa[3].w);
#pragma unroll
      for (int b = 0; b < 8; b++) {
        acc[0][b] += f0 * sf[b];
        acc[1][b] += f1 * sf[b];
        acc[2][b] += f2 * sf[b];
        acc[3][b] += f3 * sf[b];
      }
    }
  }
  // store o (fp32)
#pragma unroll
  for (int a = 0; a < 4; a++) {
    float* op = obuf + (size_t)(t0 + i0 + a) * 2048 + h * 128 + c0;
    *(float4*)op = make_float4(acc[a][0], acc[a][1], acc[a][2], acc[a][3]);
    *(float4*)(op + 4) = make_float4(acc[a][4], acc[a][5], acc[a][6], acc[a][7]);
  }
}

// ---------------- gated RMSNorm over Dv=128: ob = bf16(rms(o)*w*silu(z)) ----------------
__global__ __launch_bounds__(256) void onorm_kernel(const float* __restrict__ o,
                                                    const unsigned short* __restrict__ z,
                                                    const float* __restrict__ w,
                                                    unsigned short* __restrict__ ob) {
  const int r = blockIdx.x * 4 + (threadIdx.x >> 6);
  const int lane = threadIdx.x & 63;
  const int t = r >> 4;
  const int h = r & 15;
  const size_t base = (size_t)t * 2048 + h * 128 + lane * 2;
  float2 v = *(const float2*)(o + base);
  float s = v.x * v.x + v.y * v.y;
#pragma unroll
  for (int off = 32; off > 0; off >>= 1) s += __shfl_down(s, off);
  s = __shfl(s, 0);
  const float rn = rsqrtf(s * (1.0f / 128.0f) + 1e-5f);
  const float2 wv = *(const float2*)(w + lane * 2);
  const ushort2 zv = *(const ushort2*)(z + base);
  ushort2 res;
  res.x = f2bf(v.x * rn * wv.x * siluf(bf2f(zv.x)));
  res.y = f2bf(v.y * rn * wv.y * siluf(bf2f(zv.y)));
  *(ushort2*)(ob + base) = res;
}

// ---------------- helpers ----------------
__global__ __launch_bounds__(256) void copy_kernel(const float* __restrict__ in,
                                                   float* __restrict__ out) {
  const int i = blockIdx.x * 256 + threadIdx.x;
  ((float4*)out)[i] = ((const float4*)in)[i];
}

extern "C" void kernel_launch(void* const* d_in, const int* in_sizes, int n_in,
                              void* d_out, int out_size, void* d_ws, size_t ws_size,
                              hipStream_t stream) {
  (void)in_sizes; (void)n_in; (void)out_size;
  const float* x        = (const float*)d_in[0];
  const float* mask     = (const float*)d_in[1];
  const float* ln1_w    = (const float*)d_in[2];
  const float* qkvz_w   = (const float*)d_in[3];
  const float* ba_w     = (const float*)d_in[4];
  const float* conv_w   = (const float*)d_in[5];
  const float* A_log    = (const float*)d_in[6];
  const float* dt_bias  = (const float*)d_in[7];
  const float* o_norm_w = (const float*)d_in[8];
  const float* out_w    = (const float*)d_in[9];
  const float* ln2_w    = (const float*)d_in[10];
  const float* gate_w   = (const float*)d_in[11];
  const float* up_w     = (const float*)d_in[12];
  const float* down_w   = (const float*)d_in[13];
  float* out = (float*)d_out;

  const size_t NEED_BYTES = (size_t)75825152 * 4;
  if (ws_size < NEED_BYTES) return;

  float* ws = (float*)d_ws;
  // [0, 25165824): mixed_f32 (phase A)  ->  Wg/Wu/Wd bf16 (MLP phase)
  float* mixed_buf = ws;
  unsigned short* Wg = (unsigned short*)ws;
  unsigned short* Wu = (unsigned short*)(ws + 8388608);
  unsigned short* Wd = (unsigned short*)(ws + 16777216);
  // [25165824, 41943040): qkvz_bf16 -> u/w f32 (u becomes v_new) -> gate/comb bf16
  unsigned short* qkvz_bf = (unsigned short*)(ws + 25165824);
  float* u_buf = ws + 25165824;
  float* w_buf = ws + 33554432;
  unsigned short* gate_bf = (unsigned short*)(ws + 25165824);
  // [41943040, 46137344): z bf16
  unsigned short* z_bf = (unsigned short*)(ws + 41943040);
  // [46137344, 54525952): h_f32 -> a/t -> o_f32
  float* h_buf = ws + 46137344;
  float* a_buf = ws + 46137344;
  float* t_buf = ws + 50331648;
  float* o_buf = ws + 46137344;
  // [54525952, 58720256): h_bf16 -> o_bf16 -> h2_bf16
  unsigned short* h_bf  = (unsigned short*)(ws + 54525952);
  unsigned short* o_bf  = (unsigned short*)(ws + 54525952);
  unsigned short* h2_bf = (unsigned short*)(ws + 54525952);
  // [58720256, 62914560): attn f32
  float* attn_buf = ws + 58720256;
  // [62914560, 71303168): Wq bf16 -> Sbuf bf16 (1024 x 128 x 128)
  unsigned short* Wq = (unsigned short*)(ws + 62914560);
  unsigned short* Sb = (unsigned short*)(ws + 62914560);
  // [71303168, 73400320): Wo bf16
  unsigned short* Wo = (unsigned short*)(ws + 71303168);
  // smalls
  float* ba_buf   = ws + 73400320;
  float* beta_buf = ws + 73531392;
  float* g_buf    = ws + 73596928;
  float* gcs_buf  = ws + 73662464;
  float* edk_buf  = ws + 73728000;   // [1024][64]
  float* egq_buf  = ws + 73793536;   // [1024][64]
  float* adec_buf = ws + 73859072;   // [1024]

  rmsnorm_kernel<1><<<4096, 256, 0, stream>>>(x, ln1_w, h_buf, h_bf);
  f2b_kernel<<<8192, 256, 0, stream>>>(qkvz_w, Wq);
  gemm_bf16_kernel<0><<<dim3(64, 32), 256, 0, stream>>>(h_bf, Wq, nullptr, qkvz_bf, 4096, 8192, 2048);
  ba_gemm_kernel<<<4096, 256, 0, stream>>>(h_buf, ba_w, ba_buf);
  zcopy_kernel<<<4096, 256, 0, stream>>>(qkvz_bf, z_bf);
  conv_silu_kernel<<<24576, 256, 0, stream>>>(qkvz_bf, conv_w, mask, mixed_buf);
  l2norm_kernel<<<32768, 256, 0, stream>>>(mixed_buf);
  beta_g_kernel<<<256, 256, 0, stream>>>(ba_buf, A_log, dt_bias, mask, beta_buf, g_buf);
  gcs_kernel<<<4, 256, 0, stream>>>(g_buf, gcs_buf, edk_buf, egq_buf, adec_buf);
  pre_attn_kernel<<<1024, 256, 0, stream>>>(mixed_buf, gcs_buf, beta_buf, a_buf, attn_buf);
  pre_solve_kernel<<<1024, 256, 0, stream>>>(a_buf, beta_buf, t_buf);
  pre_uw_kernel<<<1024, 256, 0, stream>>>(mixed_buf, t_buf, gcs_buf, u_buf, w_buf);
  // minimal sequential scan: v_new (in u_buf) + per-chunk state S -> Sb (old Wq region)
  scan_kernel<<<128, 256, 0, stream>>>(mixed_buf, u_buf, w_buf, edk_buf, adec_buf, Sb);
  // parallel o computation
  ocomp_kernel<<<1024, 256, 0, stream>>>(mixed_buf, Sb, u_buf, attn_buf, egq_buf, o_buf);
  // weight converts for the back half (mixed now dead)
  f2b_kernel<<<8192, 256, 0, stream>>>(gate_w, Wg);
  f2b_kernel<<<8192, 256, 0, stream>>>(up_w, Wu);
  f2b_kernel<<<8192, 256, 0, stream>>>(down_w, Wd);
  f2b_kernel<<<2048, 256, 0, stream>>>(out_w, Wo);
  onorm_kernel<<<16384, 256, 0, stream>>>(o_buf, z_bf, o_norm_w, o_bf);
  copy_kernel<<<8192, 256, 0, stream>>>(x, out);
  gemm_bf16_kernel<1><<<dim3(16, 32), 256, 0, stream>>>(o_bf, Wo, out, nullptr, 4096, 2048, 2048);
  rmsnorm_kernel<2><<<4096, 256, 0, stream>>>(out, ln2_w, nullptr, h2_bf);
  gemm_bf16_kernel<0><<<dim3(64, 32), 256, 0, stream>>>(h2_bf, Wg, nullptr, gate_bf, 4096, 8192, 2048);
  gemm_bf16_kernel<2><<<dim3(64, 32), 256, 0, stream>>>(h2_bf, Wu, nullptr, gate_bf, 4096, 8192, 2048);
  gemm_bf16_kernel<1><<<dim3(16, 32), 256, 0, stream>>>(gate_bf, Wd, out, nullptr, 4096, 2048, 8192);
}